// Round 10
// baseline (2257.966 us; speedup 1.0000x reference)
//
#include <hip/hip_runtime.h>
#include <hip/hip_bf16.h>

#define EMBD 300
#define GG   4096
#define NLAY 5
#define KP1  320   // padded K for EMB=300 inputs (also h row stride)
#define KP2  640   // padded K for 2*EMB=600 inputs
#define NP1  640   // padded out-cols for 600
#define NP2  384   // padded out-cols for 300 (4 waves x 96)
#define WPER (NP1*KP1 + NP2*KP2)   // 450560 elems per MLP weight set

typedef unsigned short ushort_t;
typedef short short8 __attribute__((ext_vector_type(8)));
typedef short short4v __attribute__((ext_vector_type(4)));
typedef float f32x4 __attribute__((ext_vector_type(4)));

static inline int cdiv(int a, int b) { return (a + b - 1) / b; }

// ---------------- helpers ----------------

__device__ inline void dma16(const ushort_t* g, ushort_t* l) {
    __builtin_amdgcn_global_load_lds(
        (const __attribute__((address_space(1))) unsigned int*)g,
        (__attribute__((address_space(3))) unsigned int*)l, 16, 0, 0);
}

__device__ inline ushort_t bf16_of(float v) {
    union { __hip_bfloat16 b; ushort_t u; } c;
    c.b = __float2bfloat16(v);
    return c.u;
}

__device__ inline float bf2f(ushort_t u) {
    union { unsigned int i; float f; } c;
    c.i = ((unsigned int)u) << 16;
    return c.f;
}

// ---------------- init kernels ----------------

// atom encode + vn0 broadcast -> h bf16 [N][KP1]
__global__ void atom_encode_bf(const int* __restrict__ x, const float* __restrict__ aemb,
                               const float* __restrict__ vn_emb,
                               ushort_t* __restrict__ h, int N) {
    int i = blockIdx.x * blockDim.x + threadIdx.x;
    int total = N * 75;
    if (i >= total) return;
    int n = i / 75, d4 = i - n * 75;
    const int* xr = x + n * 9;
    float4 s = ((const float4*)vn_emb)[d4];   // + vn_0
    const float4* a4 = (const float4*)aemb;
#pragma unroll
    for (int f = 0; f < 9; ++f) {
        float4 v = a4[(size_t)((f << 7) + xr[f]) * 75 + d4];
        s.x += v.x; s.y += v.y; s.z += v.z; s.w += v.w;
    }
    short4v o;
    o[0] = (short)bf16_of(s.x); o[1] = (short)bf16_of(s.y);
    o[2] = (short)bf16_of(s.z); o[3] = (short)bf16_of(s.w);
    *(short4v*)(h + (size_t)n * KP1 + d4 * 4) = o;
}

__global__ void init_vn4(const float* __restrict__ vn_emb, float* __restrict__ vn) {
    int i = blockIdx.x * blockDim.x + threadIdx.x;
    if (i >= GG * 75) return;
    ((float4*)vn)[i] = ((const float4*)vn_emb)[i % 75];
}

__global__ void find_starts(const int* __restrict__ batch, int* __restrict__ starts, int N) {
    int g = blockIdx.x * blockDim.x + threadIdx.x;
    if (g > GG) return;
    int lo = 0, hi = N;
    while (lo < hi) {
        int mid = (lo + hi) >> 1;
        if (batch[mid] < g) lo = mid + 1; else hi = mid;
    }
    starts[g] = lo;
}

// bond combo table: ebsum[c][d], c=(a0<<6)|(a1<<3)|a2
__global__ void bond_combo(const float* __restrict__ bemb, float* __restrict__ ebsum) {
    int i = blockIdx.x * blockDim.x + threadIdx.x;
    if (i >= 512 * EMBD) return;
    int c = i / EMBD, d = i - c * EMBD;
    int a0 = c >> 6, a1 = (c >> 3) & 7, a2 = c & 7;
    ebsum[i] = bemb[a0 * EMBD + d] + bemb[(8 + a1) * EMBD + d] + bemb[(16 + a2) * EMBD + d];
}

// convert all 9 MLP weight sets into transposed single-bf16 planes
__global__ void conv_all(const float* __restrict__ gW1, const float* __restrict__ gW2,
                         const float* __restrict__ vW1, const float* __restrict__ vW2,
                         ushort_t* __restrict__ wh) {
    int i = blockIdx.x * blockDim.x + threadIdx.x;
    int total = WPER * 9;
    if (i >= total) return;
    int mlp = i / WPER, r = i - mlp * WPER;
    const float *W1, *W2;
    if (mlp < NLAY) {
        W1 = gW1 + (size_t)mlp * EMBD * 2 * EMBD;
        W2 = gW2 + (size_t)mlp * 2 * EMBD * EMBD;
    } else {
        int l = mlp - NLAY;
        W1 = vW1 + (size_t)l * EMBD * 2 * EMBD;
        W2 = vW2 + (size_t)l * 2 * EMBD * EMBD;
    }
    float v;
    if (r < NP1 * KP1) {
        int n = r / KP1, k = r - n * KP1;
        v = (n < 2 * EMBD && k < EMBD) ? W1[(size_t)k * (2 * EMBD) + n] : 0.f;
    } else {
        int r2 = r - NP1 * KP1;
        int n = r2 / KP2, k = r2 - n * KP2;
        v = (n < EMBD && k < 2 * EMBD) ? W2[(size_t)k * EMBD + n] : 0.f;
    }
    wh[i] = bf16_of(v);
}

// ---------------- edge bucket sort ----------------

__global__ void ecount(const int* __restrict__ ei, int* __restrict__ cnt, int E) {
    int e = blockIdx.x * blockDim.x + threadIdx.x;
    if (e >= E) return;
    atomicAdd(&cnt[ei[E + e]], 1);
}

__global__ void scan_part(const int* __restrict__ cnt, int* __restrict__ bsum, int N) {
    __shared__ int sh[256];
    int b = blockIdx.x, t = threadIdx.x;
    int base = b * 1024;
    int s = 0;
    for (int j = t; j < 1024; j += 256) {
        int idx = base + j;
        if (idx < N) s += cnt[idx];
    }
    sh[t] = s;
    __syncthreads();
    for (int d = 128; d > 0; d >>= 1) {
        if (t < d) sh[t] += sh[t + d];
        __syncthreads();
    }
    if (t == 0) bsum[b] = sh[0];
}

__global__ void scan_top(int* __restrict__ bsum, int nb) {
    __shared__ int sh[1024];
    int t = threadIdx.x;
    int v = (t < nb) ? bsum[t] : 0;
    sh[t] = v;
    __syncthreads();
    for (int d = 1; d < 1024; d <<= 1) {
        int u = (t >= d) ? sh[t - d] : 0;
        __syncthreads();
        sh[t] += u;
        __syncthreads();
    }
    if (t < nb) bsum[t] = sh[t] - v;  // exclusive
}

__global__ void scan_final(const int* __restrict__ cnt, const int* __restrict__ bsum,
                           int* __restrict__ estart, int* __restrict__ cursor, int N, int E) {
    __shared__ int sh[256];
    int b = blockIdx.x, t = threadIdx.x;
    int base = b * 1024 + t * 4;
    int c[4];
    int s = 0;
#pragma unroll
    for (int j = 0; j < 4; ++j) {
        int idx = base + j;
        c[j] = (idx < N) ? cnt[idx] : 0;
        s += c[j];
    }
    sh[t] = s;
    __syncthreads();
    for (int d = 1; d < 256; d <<= 1) {
        int u = (t >= d) ? sh[t - d] : 0;
        __syncthreads();
        sh[t] += u;
        __syncthreads();
    }
    int run = sh[t] - s + bsum[b];
#pragma unroll
    for (int j = 0; j < 4; ++j) {
        int idx = base + j;
        if (idx < N) { estart[idx] = run; cursor[idx] = run; run += c[j]; }
    }
    if (b == 0 && t == 0) estart[N] = E;
}

__global__ void escatter(const int* __restrict__ ei, const int* __restrict__ ea,
                         int* __restrict__ cursor, int2* __restrict__ epack, int E) {
    int e = blockIdx.x * blockDim.x + threadIdx.x;
    if (e >= E) return;
    int c = ei[E + e];
    int p = atomicAdd(&cursor[c], 1);
    epack[p] = make_int2(ei[e], (ea[3 * e] << 6) | (ea[3 * e + 1] << 3) | ea[3 * e + 2]);
}

// ---------------- per-layer elementwise (h is bf16 [N][KP1], already includes vn) ----------------

// read-only pool: vnaB[g] = bf16(segment_sum(h) + vn[g])
__global__ void pool_only(const ushort_t* __restrict__ h, const float* __restrict__ vn,
                          const int* __restrict__ starts, ushort_t* __restrict__ vnaB) {
    int g = blockIdx.x;
    int t = threadIdx.x;   // 320
    if (t >= EMBD) return;
    int s0 = starts[g], s1 = starts[g + 1];
    float s = 0.f;
    for (int n = s0; n < s1; ++n) s += bf2f(h[(size_t)n * KP1 + t]);
    vnaB[(size_t)g * KP1 + t] = bf16_of(s + vn[(size_t)g * EMBD + t]);
}

__global__ void pool_mean(const ushort_t* __restrict__ h, const int* __restrict__ starts,
                          float* __restrict__ out) {
    int g = blockIdx.x;
    int t = threadIdx.x;
    if (t >= EMBD) return;
    int s0 = starts[g], s1 = starts[g + 1];
    float s = 0.f;
    for (int n = s0; n < s1; ++n) s += bf2f(h[(size_t)n * KP1 + t]);
    float cnt = (float)(s1 - s0);
    out[(size_t)g * EMBD + t] = s / fmaxf(cnt, 1.0f);
}

// ---------------- fused aggregate ----------------
#define NPB 4   // nodes per block; blockDim = NPB*80 = 320

__global__ void aggregate(const ushort_t* __restrict__ h, const float* __restrict__ ebsum,
                          const int* __restrict__ estart, const int2* __restrict__ epack,
                          const float* __restrict__ epsp,
                          ushort_t* __restrict__ aggB, int N) {
    int n = blockIdx.x * NPB + threadIdx.x / 80;
    int slot = threadIdx.x % 80;
    if (n >= N) return;
    float4 acc = make_float4(0.f, 0.f, 0.f, 0.f);
    if (slot < 75) {
        const float4* b4 = (const float4*)ebsum;
        float ce = 1.0f + *epsp;
        short4v hv = *(const short4v*)(h + (size_t)n * KP1 + slot * 4);
        acc.x = ce * bf2f((ushort_t)hv[0]);
        acc.y = ce * bf2f((ushort_t)hv[1]);
        acc.z = ce * bf2f((ushort_t)hv[2]);
        acc.w = ce * bf2f((ushort_t)hv[3]);
        int p0 = estart[n], p1 = estart[n + 1];
        for (int p = p0; p < p1; ++p) {
            int2 ep = epack[p];
            short4v xv = *(const short4v*)(h + (size_t)ep.x * KP1 + slot * 4);
            float4 ev = b4[(size_t)ep.y * 75 + slot];
            acc.x += fmaxf(bf2f((ushort_t)xv[0]) + ev.x, 0.f);
            acc.y += fmaxf(bf2f((ushort_t)xv[1]) + ev.y, 0.f);
            acc.z += fmaxf(bf2f((ushort_t)xv[2]) + ev.z, 0.f);
            acc.w += fmaxf(bf2f((ushort_t)xv[3]) + ev.w, 0.f);
        }
    }
    short4v bv4;
    bv4[0] = (short)bf16_of(acc.x);
    bv4[1] = (short)bf16_of(acc.y);
    bv4[2] = (short)bf16_of(acc.z);
    bv4[3] = (short)bf16_of(acc.w);
    *(short4v*)(aggB + (size_t)n * KP1 + slot * 4) = bv4;
}

// ---------------- fused 2-GEMM MLP: out = bn2( relu(bn1(A@W1)) @ W2 ) [+relu] [+vn[batch]] ----------------
// Block = 64 rows. A[64][320] staged in LDS once; 5 chunks of 128 t-cols:
// GEMM1 (W1 frags from L2 global) -> bn1+relu -> t-chunk in LDS -> GEMM2 partial (W2 from L2).
// Wave w: GEMM1 cols w*32+[0,32), GEMM2 out cols w*96+[0,96). No intermediate HBM traffic.

__global__ __launch_bounds__(256, 2) void fused_mlp(
    const ushort_t* __restrict__ A,    // [M][KP1] bf16 (pad cols zero)
    const ushort_t* __restrict__ W1,   // [NP1][KP1] bf16T
    const ushort_t* __restrict__ W2,   // [NP2][KP2] bf16T
    const float* __restrict__ b1, const float* __restrict__ g1,
    const float* __restrict__ bb1, const float* __restrict__ bm1, const float* __restrict__ bv1,
    const float* __restrict__ b2, const float* __restrict__ g2,
    const float* __restrict__ bb2, const float* __restrict__ bm2, const float* __restrict__ bv2,
    int M, int relu2,
    const float* __restrict__ vnadd, const int* __restrict__ batch,
    ushort_t* __restrict__ outB,       // [M][KP1] bf16, or null
    float* __restrict__ outF)          // [M][EMBD] fp32, or null
{
    __shared__ ushort_t sA[10 * 64 * 32];   // [ktile][64 rows][32k] 64B-granule swizzle: 40 KB
    __shared__ ushort_t tL[64 * 136];       // t chunk [64][136 pad]: 17.4 KB  (57.4 KB -> 2 blk/CU)

    const int tid = threadIdx.x;
    const int lane = tid & 63;
    const int w = tid >> 6;
    const int m0 = blockIdx.x * 64;
    const int q = lane >> 4;
    const int c16 = lane & 15;

    // ---- stage A[64][320]: slot s=tid covers (m=s>>2, q'=s&3) per k-tile ----
    {
        int m = tid >> 2, qp = tid & 3;
        int q0 = (qp - (m >> 1)) & 3;
        int msrc = m0 + m; if (msrc >= M) msrc = M - 1;
        const ushort_t* gA = A + (size_t)msrc * KP1 + 8 * q0;
        int lb = w * 512;   // wave-uniform LDS base within each 2048-ushort section
#pragma unroll
        for (int kt = 0; kt < 10; ++kt)
            dma16(gA + kt * 32, sA + kt * 2048 + lb);
    }
    __syncthreads();

    f32x4 acc2[4][6];
#pragma unroll
    for (int a = 0; a < 4; ++a)
#pragma unroll
        for (int b = 0; b < 6; ++b) acc2[a][b] = (f32x4)(0.f);

    for (int c = 0; c < 5; ++c) {
        // BN1 constants for this wave's 2 col-tiles
        float sc1[2], sh1[2];
#pragma unroll
        for (int uu = 0; uu < 2; ++uu) {
            int col = c * 128 + w * 32 + uu * 16 + c16;
            if (col < 2 * EMBD) {
                float s = g1[col] * rsqrtf(bv1[col] + 1e-5f);
                sc1[uu] = s;
                sh1[uu] = bb1[col] + (b1[col] - bm1[col]) * s;
            } else { sc1[uu] = 0.f; sh1[uu] = 0.f; }
        }
        // ---- GEMM1: t_cols [c*128 + w*32, +32), K = 320 ----
        f32x4 acc1[4][2];
#pragma unroll
        for (int a = 0; a < 4; ++a) { acc1[a][0] = (f32x4)(0.f); acc1[a][1] = (f32x4)(0.f); }
        for (int kt = 0; kt < 10; ++kt) {
            short8 bf[2];
#pragma unroll
            for (int uu = 0; uu < 2; ++uu) {
                int ncol = c * 128 + w * 32 + uu * 16 + c16;
                bf[uu] = *(const short8*)(W1 + (size_t)ncol * KP1 + kt * 32 + q * 8);
            }
            short8 af[4];
#pragma unroll
            for (int tt = 0; tt < 4; ++tt) {
                int m2 = tt * 16 + c16;
                int q2 = (q + (m2 >> 1)) & 3;
                af[tt] = *(const short8*)(sA + kt * 2048 + m2 * 32 + q2 * 8);
            }
#pragma unroll
            for (int tt = 0; tt < 4; ++tt)
#pragma unroll
                for (int uu = 0; uu < 2; ++uu)
                    acc1[tt][uu] = __builtin_amdgcn_mfma_f32_16x16x32_bf16(af[tt], bf[uu], acc1[tt][uu], 0, 0, 0);
        }
        // ---- bn1+relu -> t chunk in LDS (C-layout write: row=tt*16+q*4+r, col=w*32+uu*16+c16) ----
#pragma unroll
        for (int uu = 0; uu < 2; ++uu) {
            int col = w * 32 + uu * 16 + c16;
#pragma unroll
            for (int tt = 0; tt < 4; ++tt)
#pragma unroll
                for (int r = 0; r < 4; ++r) {
                    int row = tt * 16 + q * 4 + r;
                    float y = fmaxf(acc1[tt][uu][r] * sc1[uu] + sh1[uu], 0.f);
                    tL[row * 136 + col] = bf16_of(y);
                }
        }
        __syncthreads();
        // ---- GEMM2 partial: K-chunk = 128 (4 k-tiles) ----
        for (int kt2 = 0; kt2 < 4; ++kt2) {
            short8 bf2[6];
#pragma unroll
            for (int uu = 0; uu < 6; ++uu) {
                int ncol = w * 96 + uu * 16 + c16;
                bf2[uu] = *(const short8*)(W2 + (size_t)ncol * KP2 + c * 128 + kt2 * 32 + q * 8);
            }
            short8 af2[4];
#pragma unroll
            for (int tt = 0; tt < 4; ++tt) {
                int m2 = tt * 16 + c16;
                af2[tt] = *(const short8*)(tL + m2 * 136 + kt2 * 32 + q * 8);
            }
#pragma unroll
            for (int tt = 0; tt < 4; ++tt)
#pragma unroll
                for (int uu = 0; uu < 6; ++uu)
                    acc2[tt][uu] = __builtin_amdgcn_mfma_f32_16x16x32_bf16(af2[tt], bf2[uu], acc2[tt][uu], 0, 0, 0);
        }
        __syncthreads();   // protect tL before next chunk overwrites
    }

    // ---- epilogue: bn2 (+relu2) (+vn[batch]) ----
    float sc2[6], sh2[6];
#pragma unroll
    for (int uu = 0; uu < 6; ++uu) {
        int gn = w * 96 + uu * 16 + c16;
        if (gn < EMBD) {
            float s = g2[gn] * rsqrtf(bv2[gn] + 1e-5f);
            sc2[uu] = s;
            sh2[uu] = bb2[gn] + (b2[gn] - bm2[gn]) * s;
        } else { sc2[uu] = 0.f; sh2[uu] = 0.f; }
    }
#pragma unroll
    for (int tt = 0; tt < 4; ++tt)
#pragma unroll
        for (int r = 0; r < 4; ++r) {
            int gm = m0 + tt * 16 + q * 4 + r;
            if (gm >= M) continue;
            const float* vrow = vnadd ? (vnadd + (size_t)batch[gm] * EMBD) : nullptr;
#pragma unroll
            for (int uu = 0; uu < 6; ++uu) {
                int gn = w * 96 + uu * 16 + c16;
                float y = acc2[tt][uu][r] * sc2[uu] + sh2[uu];
                if (relu2) y = fmaxf(y, 0.f);
                if (vrow && gn < EMBD) y += vrow[gn];
                if (outB) {
                    if (gn < KP1) outB[(size_t)gm * KP1 + gn] = bf16_of(y);  // pads get 0
                } else {
                    if (gn < EMBD) outF[(size_t)gm * EMBD + gn] = y;
                }
            }
        }
}

// ---------------- entry ----------------

extern "C" void kernel_launch(void* const* d_in, const int* in_sizes, int n_in,
                              void* d_out, int out_size, void* d_ws, size_t ws_size,
                              hipStream_t stream) {
    const int*   x        = (const int*)d_in[0];
    const int*   ei       = (const int*)d_in[1];
    const int*   ea       = (const int*)d_in[2];
    const int*   batch    = (const int*)d_in[3];
    const float* atom_emb = (const float*)d_in[4];
    const float* bond_emb = (const float*)d_in[5];
    const float* vn_emb   = (const float*)d_in[6];
    const float* gin_eps  = (const float*)d_in[7];
    const float* gin_W1   = (const float*)d_in[8];
    const float* gin_b1   = (const float*)d_in[9];
    const float* gin_bn1g = (const float*)d_in[10];
    const float* gin_bn1b = (const float*)d_in[11];
    const float* gin_bn1m = (const float*)d_in[12];
    const float* gin_bn1v = (const float*)d_in[13];
    const float* gin_W2   = (const float*)d_in[14];
    const float* gin_b2   = (const float*)d_in[15];
    const float* bn_g     = (const float*)d_in[16];
    const float* bn_b     = (const float*)d_in[17];
    const float* bn_m     = (const float*)d_in[18];
    const float* bn_v     = (const float*)d_in[19];
    const float* vn_W1    = (const float*)d_in[20];
    const float* vn_b1    = (const float*)d_in[21];
    const float* vn_bn1g  = (const float*)d_in[22];
    const float* vn_bn1b  = (const float*)d_in[23];
    const float* vn_bn1m  = (const float*)d_in[24];
    const float* vn_bn1v  = (const float*)d_in[25];
    const float* vn_W2    = (const float*)d_in[26];
    const float* vn_b2    = (const float*)d_in[27];
    const float* vn_bn2g  = (const float*)d_in[28];
    const float* vn_bn2b  = (const float*)d_in[29];
    const float* vn_bn2m  = (const float*)d_in[30];
    const float* vn_bn2v  = (const float*)d_in[31];

    const int N = in_sizes[3];
    const int E = in_sizes[1] / 2;
    const int NB = cdiv(N, 1024);

    // ---- workspace layout (bytes); fixed ~147 MB of the ~256 MiB budget; no chunk buffer ----
    char* base = (char*)d_ws;
    size_t off = 0;
    ushort_t* hbuf = (ushort_t*)(base + off); off += (size_t)N * KP1 * 2;    // 64 MB
    ushort_t* aggB = (ushort_t*)(base + off); off += (size_t)N * KP1 * 2;    // 64 MB
    float* vnbuf   = (float*)(base + off);    off += (size_t)GG * EMBD * 4;  // 4.9 MB
    int*   starts  = (int*)(base + off);      off += 4104 * 4;
    int*   cnt     = (int*)(base + off);      off += (size_t)N * 4;
    int*   cursor  = (int*)(base + off);      off += (size_t)N * 4;
    int*   estart  = (int*)(base + off);      off += ((size_t)N + 8) * 4;
    int*   bsum    = (int*)(base + off);      off += 1032 * 4;
    int2*  epack   = (int2*)(base + off);     off += (size_t)E * 8;          // 2 MB
    float* ebsum   = (float*)(base + off);    off += (size_t)512 * EMBD * 4; // 0.6 MB
    ushort_t* whA  = (ushort_t*)(base + off); off += (size_t)9 * WPER * 2;   // 8.1 MB
    ushort_t* vnaB = (ushort_t*)(base + off); off += (size_t)GG * KP1 * 2;   // 2.6 MB

    const int BLK = 256;
    int ne4 = N * 75;

    // ---- one-time init ----
    find_starts<<<cdiv(GG + 1, BLK), BLK, 0, stream>>>(batch, starts, N);
    atom_encode_bf<<<cdiv(ne4, BLK), BLK, 0, stream>>>(x, atom_emb, vn_emb, hbuf, N);
    init_vn4<<<cdiv(GG * 75, BLK), BLK, 0, stream>>>(vn_emb, vnbuf);
    bond_combo<<<cdiv(512 * EMBD, BLK), BLK, 0, stream>>>(bond_emb, ebsum);
    conv_all<<<cdiv(9 * WPER, BLK), BLK, 0, stream>>>(gin_W1, gin_W2, vn_W1, vn_W2, whA);
    hipMemsetAsync(cnt, 0, (size_t)N * 4, stream);
    hipMemsetAsync(vnaB, 0, (size_t)GG * KP1 * 2, stream);  // zero pad cols (re-poisoned each call)
    ecount<<<cdiv(E, BLK), BLK, 0, stream>>>(ei, cnt, E);
    scan_part<<<NB, 256, 0, stream>>>(cnt, bsum, N);
    scan_top<<<1, 1024, 0, stream>>>(bsum, NB);
    scan_final<<<NB, 256, 0, stream>>>(cnt, bsum, estart, cursor, N, E);
    escatter<<<cdiv(E, BLK), BLK, 0, stream>>>(ei, ea, cursor, epack, E);

    for (int l = 0; l < NLAY; ++l) {
        int last = (l == NLAY - 1);

        if (!last) {
            // vnaB = pool(h) + vn_l  (h already contains vn_l)
            pool_only<<<GG, 320, 0, stream>>>(hbuf, vnbuf, starts, vnaB);
            // vn_{l+1} = relu(bn2(mlp(vnaB)))  -> vnbuf (fp32)
            const ushort_t* w1 = whA + (size_t)(NLAY + l) * WPER;
            const ushort_t* w2 = w1 + NP1 * KP1;
            fused_mlp<<<cdiv(GG, 64), 256, 0, stream>>>(
                vnaB, w1, w2,
                vn_b1 + (size_t)l * 2 * EMBD, vn_bn1g + (size_t)l * 2 * EMBD,
                vn_bn1b + (size_t)l * 2 * EMBD, vn_bn1m + (size_t)l * 2 * EMBD,
                vn_bn1v + (size_t)l * 2 * EMBD,
                vn_b2 + (size_t)l * EMBD, vn_bn2g + (size_t)l * EMBD,
                vn_bn2b + (size_t)l * EMBD, vn_bn2m + (size_t)l * EMBD,
                vn_bn2v + (size_t)l * EMBD,
                GG, 1, nullptr, nullptr,
                nullptr, vnbuf);
        }

        // aggB = bf16( (1+eps)h + sum relu(h[src]+bond) )
        aggregate<<<cdiv(N, NPB), NPB * 80, 0, stream>>>(
            hbuf, ebsum, estart, epack, gin_eps + l, aggB, N);

        // h_out = bn(mlp(aggB)) (+relu, +vn_{l+1} unless last)
        {
            const ushort_t* w1 = whA + (size_t)l * WPER;
            const ushort_t* w2 = w1 + NP1 * KP1;
            fused_mlp<<<cdiv(N, 64), 256, 0, stream>>>(
                aggB, w1, w2,
                gin_b1 + (size_t)l * 2 * EMBD, gin_bn1g + (size_t)l * 2 * EMBD,
                gin_bn1b + (size_t)l * 2 * EMBD, gin_bn1m + (size_t)l * 2 * EMBD,
                gin_bn1v + (size_t)l * 2 * EMBD,
                gin_b2 + (size_t)l * EMBD, bn_g + (size_t)l * EMBD,
                bn_b + (size_t)l * EMBD, bn_m + (size_t)l * EMBD,
                bn_v + (size_t)l * EMBD,
                N, last ? 0 : 1,
                last ? nullptr : vnbuf, batch,
                hbuf, nullptr);
        }
    }

    pool_mean<<<GG, 320, 0, stream>>>(hbuf, starts, (float*)d_out);
}

// Round 11
// 2136.644 us; speedup vs baseline: 1.0568x; 1.0568x over previous
//
#include <hip/hip_runtime.h>
#include <hip/hip_bf16.h>

#define EMBD 300
#define GG   4096
#define NLAY 5
#define KP1  320   // padded K for EMB=300 inputs (also h row stride)
#define KP2  640   // padded K for 2*EMB=600 inputs
#define NP1  640   // padded out-cols for 600
#define NP2  384   // padded out-cols for 300 (3 x 128)
#define WPER (NP1*KP1 + NP2*KP2)   // 450560 elems per MLP weight set

typedef unsigned short ushort_t;
typedef short short8 __attribute__((ext_vector_type(8)));
typedef short short4v __attribute__((ext_vector_type(4)));
typedef float f32x4 __attribute__((ext_vector_type(4)));

static inline int cdiv(int a, int b) { return (a + b - 1) / b; }

// ---------------- helpers ----------------

__device__ inline void dma16(const ushort_t* g, ushort_t* l) {
    __builtin_amdgcn_global_load_lds(
        (const __attribute__((address_space(1))) unsigned int*)g,
        (__attribute__((address_space(3))) unsigned int*)l, 16, 0, 0);
}

__device__ inline ushort_t bf16_of(float v) {
    union { __hip_bfloat16 b; ushort_t u; } c;
    c.b = __float2bfloat16(v);
    return c.u;
}

__device__ inline float bf2f(ushort_t u) {
    union { unsigned int i; float f; } c;
    c.i = ((unsigned int)u) << 16;
    return c.f;
}

// ---------------- init kernels ----------------

// atom encode + vn0 broadcast -> h bf16 [N][KP1]
__global__ void atom_encode_bf(const int* __restrict__ x, const float* __restrict__ aemb,
                               const float* __restrict__ vn_emb,
                               ushort_t* __restrict__ h, int N) {
    int i = blockIdx.x * blockDim.x + threadIdx.x;
    int total = N * 75;
    if (i >= total) return;
    int n = i / 75, d4 = i - n * 75;
    const int* xr = x + n * 9;
    float4 s = ((const float4*)vn_emb)[d4];   // + vn_0
    const float4* a4 = (const float4*)aemb;
#pragma unroll
    for (int f = 0; f < 9; ++f) {
        float4 v = a4[(size_t)((f << 7) + xr[f]) * 75 + d4];
        s.x += v.x; s.y += v.y; s.z += v.z; s.w += v.w;
    }
    short4v o;
    o[0] = (short)bf16_of(s.x); o[1] = (short)bf16_of(s.y);
    o[2] = (short)bf16_of(s.z); o[3] = (short)bf16_of(s.w);
    *(short4v*)(h + (size_t)n * KP1 + d4 * 4) = o;
}

__global__ void init_vn4(const float* __restrict__ vn_emb, float* __restrict__ vn) {
    int i = blockIdx.x * blockDim.x + threadIdx.x;
    if (i >= GG * 75) return;
    ((float4*)vn)[i] = ((const float4*)vn_emb)[i % 75];
}

__global__ void find_starts(const int* __restrict__ batch, int* __restrict__ starts, int N) {
    int g = blockIdx.x * blockDim.x + threadIdx.x;
    if (g > GG) return;
    int lo = 0, hi = N;
    while (lo < hi) {
        int mid = (lo + hi) >> 1;
        if (batch[mid] < g) lo = mid + 1; else hi = mid;
    }
    starts[g] = lo;
}

// bond combo table: ebsum[c][d], c=(a0<<6)|(a1<<3)|a2
__global__ void bond_combo(const float* __restrict__ bemb, float* __restrict__ ebsum) {
    int i = blockIdx.x * blockDim.x + threadIdx.x;
    if (i >= 512 * EMBD) return;
    int c = i / EMBD, d = i - c * EMBD;
    int a0 = c >> 6, a1 = (c >> 3) & 7, a2 = c & 7;
    ebsum[i] = bemb[a0 * EMBD + d] + bemb[(8 + a1) * EMBD + d] + bemb[(16 + a2) * EMBD + d];
}

// convert all 9 MLP weight sets into transposed single-bf16 planes
__global__ void conv_all(const float* __restrict__ gW1, const float* __restrict__ gW2,
                         const float* __restrict__ vW1, const float* __restrict__ vW2,
                         ushort_t* __restrict__ wh) {
    int i = blockIdx.x * blockDim.x + threadIdx.x;
    int total = WPER * 9;
    if (i >= total) return;
    int mlp = i / WPER, r = i - mlp * WPER;
    const float *W1, *W2;
    if (mlp < NLAY) {
        W1 = gW1 + (size_t)mlp * EMBD * 2 * EMBD;
        W2 = gW2 + (size_t)mlp * 2 * EMBD * EMBD;
    } else {
        int l = mlp - NLAY;
        W1 = vW1 + (size_t)l * EMBD * 2 * EMBD;
        W2 = vW2 + (size_t)l * 2 * EMBD * EMBD;
    }
    float v;
    if (r < NP1 * KP1) {
        int n = r / KP1, k = r - n * KP1;
        v = (n < 2 * EMBD && k < EMBD) ? W1[(size_t)k * (2 * EMBD) + n] : 0.f;
    } else {
        int r2 = r - NP1 * KP1;
        int n = r2 / KP2, k = r2 - n * KP2;
        v = (n < EMBD && k < 2 * EMBD) ? W2[(size_t)k * EMBD + n] : 0.f;
    }
    wh[i] = bf16_of(v);
}

// ---------------- edge bucket sort ----------------

__global__ void ecount(const int* __restrict__ ei, int* __restrict__ cnt, int E) {
    int e = blockIdx.x * blockDim.x + threadIdx.x;
    if (e >= E) return;
    atomicAdd(&cnt[ei[E + e]], 1);
}

__global__ void scan_part(const int* __restrict__ cnt, int* __restrict__ bsum, int N) {
    __shared__ int sh[256];
    int b = blockIdx.x, t = threadIdx.x;
    int base = b * 1024;
    int s = 0;
    for (int j = t; j < 1024; j += 256) {
        int idx = base + j;
        if (idx < N) s += cnt[idx];
    }
    sh[t] = s;
    __syncthreads();
    for (int d = 128; d > 0; d >>= 1) {
        if (t < d) sh[t] += sh[t + d];
        __syncthreads();
    }
    if (t == 0) bsum[b] = sh[0];
}

__global__ void scan_top(int* __restrict__ bsum, int nb) {
    __shared__ int sh[1024];
    int t = threadIdx.x;
    int v = (t < nb) ? bsum[t] : 0;
    sh[t] = v;
    __syncthreads();
    for (int d = 1; d < 1024; d <<= 1) {
        int u = (t >= d) ? sh[t - d] : 0;
        __syncthreads();
        sh[t] += u;
        __syncthreads();
    }
    if (t < nb) bsum[t] = sh[t] - v;  // exclusive
}

__global__ void scan_final(const int* __restrict__ cnt, const int* __restrict__ bsum,
                           int* __restrict__ estart, int* __restrict__ cursor, int N, int E) {
    __shared__ int sh[256];
    int b = blockIdx.x, t = threadIdx.x;
    int base = b * 1024 + t * 4;
    int c[4];
    int s = 0;
#pragma unroll
    for (int j = 0; j < 4; ++j) {
        int idx = base + j;
        c[j] = (idx < N) ? cnt[idx] : 0;
        s += c[j];
    }
    sh[t] = s;
    __syncthreads();
    for (int d = 1; d < 256; d <<= 1) {
        int u = (t >= d) ? sh[t - d] : 0;
        __syncthreads();
        sh[t] += u;
        __syncthreads();
    }
    int run = sh[t] - s + bsum[b];
#pragma unroll
    for (int j = 0; j < 4; ++j) {
        int idx = base + j;
        if (idx < N) { estart[idx] = run; cursor[idx] = run; run += c[j]; }
    }
    if (b == 0 && t == 0) estart[N] = E;
}

__global__ void escatter(const int* __restrict__ ei, const int* __restrict__ ea,
                         int* __restrict__ cursor, int2* __restrict__ epack, int E) {
    int e = blockIdx.x * blockDim.x + threadIdx.x;
    if (e >= E) return;
    int c = ei[E + e];
    int p = atomicAdd(&cursor[c], 1);
    epack[p] = make_int2(ei[e], (ea[3 * e] << 6) | (ea[3 * e + 1] << 3) | ea[3 * e + 2]);
}

// ---------------- per-layer elementwise (h is bf16 [N][KP1], always includes vn) ----------------

// read-only pool: vnaB[g] = bf16(segment_sum(h) + vn[g])
__global__ void pool_only(const ushort_t* __restrict__ h, const float* __restrict__ vn,
                          const int* __restrict__ starts, ushort_t* __restrict__ vnaB) {
    int g = blockIdx.x;
    int t = threadIdx.x;   // 320
    if (t >= EMBD) return;
    int s0 = starts[g], s1 = starts[g + 1];
    float s = 0.f;
    for (int n = s0; n < s1; ++n) s += bf2f(h[(size_t)n * KP1 + t]);
    vnaB[(size_t)g * KP1 + t] = bf16_of(s + vn[(size_t)g * EMBD + t]);
}

__global__ void pool_mean(const ushort_t* __restrict__ h, const int* __restrict__ starts,
                          float* __restrict__ out) {
    int g = blockIdx.x;
    int t = threadIdx.x;
    if (t >= EMBD) return;
    int s0 = starts[g], s1 = starts[g + 1];
    float s = 0.f;
    for (int n = s0; n < s1; ++n) s += bf2f(h[(size_t)n * KP1 + t]);
    float cnt = (float)(s1 - s0);
    out[(size_t)g * EMBD + t] = s / fmaxf(cnt, 1.0f);
}

// ---------------- fused aggregate ----------------
#define NPB 4   // nodes per block; blockDim = NPB*80 = 320

__global__ void aggregate(const ushort_t* __restrict__ h, const float* __restrict__ ebsum,
                          const int* __restrict__ estart, const int2* __restrict__ epack,
                          const float* __restrict__ epsp,
                          ushort_t* __restrict__ aggB, int N) {
    int n = blockIdx.x * NPB + threadIdx.x / 80;
    int slot = threadIdx.x % 80;
    if (n >= N) return;
    float4 acc = make_float4(0.f, 0.f, 0.f, 0.f);
    if (slot < 75) {
        const float4* b4 = (const float4*)ebsum;
        float ce = 1.0f + *epsp;
        short4v hv = *(const short4v*)(h + (size_t)n * KP1 + slot * 4);
        acc.x = ce * bf2f((ushort_t)hv[0]);
        acc.y = ce * bf2f((ushort_t)hv[1]);
        acc.z = ce * bf2f((ushort_t)hv[2]);
        acc.w = ce * bf2f((ushort_t)hv[3]);
        int p0 = estart[n], p1 = estart[n + 1];
        for (int p = p0; p < p1; ++p) {
            int2 ep = epack[p];
            short4v xv = *(const short4v*)(h + (size_t)ep.x * KP1 + slot * 4);
            float4 ev = b4[(size_t)ep.y * 75 + slot];
            acc.x += fmaxf(bf2f((ushort_t)xv[0]) + ev.x, 0.f);
            acc.y += fmaxf(bf2f((ushort_t)xv[1]) + ev.y, 0.f);
            acc.z += fmaxf(bf2f((ushort_t)xv[2]) + ev.z, 0.f);
            acc.w += fmaxf(bf2f((ushort_t)xv[3]) + ev.w, 0.f);
        }
    }
    short4v bv4;
    bv4[0] = (short)bf16_of(acc.x);
    bv4[1] = (short)bf16_of(acc.y);
    bv4[2] = (short)bf16_of(acc.z);
    bv4[3] = (short)bf16_of(acc.w);
    *(short4v*)(aggB + (size_t)n * KP1 + slot * 4) = bv4;
}

// ---------------- MFMA GEMM: bf16 A,B; 128x128 tile; 2-stage LDS; XCD swizzle ----------------
// optional epilogue vn-add: y += vnadd[batchp[row]][col]
#define BMg 128
#define BNg 128

__global__ __launch_bounds__(256) void gemm_as(
    const ushort_t* __restrict__ A, int KP,
    const ushort_t* __restrict__ B,
    const float* __restrict__ bias, const float* __restrict__ gg,
    const float* __restrict__ bb, const float* __restrict__ bm,
    const float* __restrict__ bv,
    int Mc, int NnReal, int relu, int nb, int mb,
    const float* __restrict__ vnadd, const int* __restrict__ batchp,
    float* __restrict__ outF, int ldF,
    ushort_t* __restrict__ outB, int ldP)
{
    __shared__ ushort_t sA[2][BMg * 32];   // 2 x 8 KB
    __shared__ ushort_t sB[2][BNg * 32];   // 2 x 8 KB  (32 KB total -> 5 blocks/CU)

    // XCD-aware swizzle: same m-strip lands consecutively on one XCD
    int id = blockIdx.x;
    int hi = id / (8 * nb);
    int rem = id - hi * 8 * nb;
    int xcd = rem & 7;
    int nblk = rem >> 3;
    int mblk = hi * 8 + xcd;
    if (mblk >= mb) return;

    const int tid = threadIdx.x;
    const int lane = tid & 63;
    const int w = tid >> 6;
    const int m0 = mblk * BMg;
    const int n0 = nblk * BNg;
    const int wm = (w & 1) * 64;
    const int wn = (w >> 1) * 64;

    const ushort_t* gA[2];
    const ushort_t* gB[2];
    int lbase[2];
#pragma unroll
    for (int i = 0; i < 2; ++i) {
        int s = tid + 256 * i;
        int m = s >> 2, qp = s & 3;
        int q = (qp - (m >> 1)) & 3;
        int msrc = (m0 + m < Mc) ? (m0 + m) : (Mc - 1);
        gA[i] = A + (size_t)msrc * KP + 8 * q;
        gB[i] = B + (size_t)(n0 + m) * KP + 8 * q;   // B rows fully padded
        lbase[i] = (w * 64 + 256 * i) * 8;
    }

    f32x4 acc[4][4];
#pragma unroll
    for (int a = 0; a < 4; ++a)
#pragma unroll
        for (int b = 0; b < 4; ++b) acc[a][b] = (f32x4)(0.f);

    const int q = lane >> 4;
    const int c16 = lane & 15;
    const int kt = KP >> 5;

    // prefetch tile 0 -> stage 0
#pragma unroll
    for (int i = 0; i < 2; ++i) {
        dma16(gA[i], sA[0] + lbase[i]); gA[i] += 32;
        dma16(gB[i], sB[0] + lbase[i]); gB[i] += 32;
    }
    __syncthreads();

    for (int t = 0; t < kt; ++t) {
        int cur = t & 1, nxt = cur ^ 1;
        if (t + 1 < kt) {
#pragma unroll
            for (int i = 0; i < 2; ++i) {
                dma16(gA[i], sA[nxt] + lbase[i]); gA[i] += 32;
                dma16(gB[i], sB[nxt] + lbase[i]); gB[i] += 32;
            }
        }
        short8 av[4], bhv[4];
#pragma unroll
        for (int tt = 0; tt < 4; ++tt) {
            int m = wm + tt * 16 + c16;
            int q2 = (q + (m >> 1)) & 3;
            av[tt] = *(const short8*)(sA[cur] + m * 32 + q2 * 8);
        }
#pragma unroll
        for (int uu = 0; uu < 4; ++uu) {
            int n = wn + uu * 16 + c16;
            int q2 = (q + (n >> 1)) & 3;
            bhv[uu] = *(const short8*)(sB[cur] + n * 32 + q2 * 8);
        }
#pragma unroll
        for (int tt = 0; tt < 4; ++tt)
#pragma unroll
            for (int uu = 0; uu < 4; ++uu)
                acc[tt][uu] = __builtin_amdgcn_mfma_f32_16x16x32_bf16(av[tt], bhv[uu], acc[tt][uu], 0, 0, 0);
        __syncthreads();
    }

    // ---- epilogue: bn (+relu) (+vn[batch]); C/D layout col=lane&15, row=q*4+r ----
    float sc[4], sh[4];
#pragma unroll
    for (int uu = 0; uu < 4; ++uu) {
        int gn = n0 + wn + uu * 16 + c16;
        if (gn < NnReal) {
            float s = gg[gn] * rsqrtf(bv[gn] + 1e-5f);
            sc[uu] = s;
            sh[uu] = bb[gn] + (bias[gn] - bm[gn]) * s;
        } else { sc[uu] = 0.f; sh[uu] = 0.f; }
    }
#pragma unroll
    for (int tt = 0; tt < 4; ++tt)
#pragma unroll
        for (int r = 0; r < 4; ++r) {
            int gm = m0 + wm + tt * 16 + q * 4 + r;
            if (gm >= Mc) continue;
            const float* vrow = vnadd ? (vnadd + (size_t)batchp[gm] * EMBD) : nullptr;
#pragma unroll
            for (int uu = 0; uu < 4; ++uu) {
                int gn = n0 + wn + uu * 16 + c16;
                float y = acc[tt][uu][r] * sc[uu] + sh[uu];
                if (relu) y = fmaxf(y, 0.f);
                if (vrow && gn < EMBD) y += vrow[gn];
                if (outF) {
                    if (gn < NnReal) outF[(size_t)gm * ldF + gn] = y;
                } else {
                    if (gn < ldP) outB[(size_t)gm * ldP + gn] = bf16_of(y);  // pads get 0
                }
            }
        }
}

// ---------------- host-side MLP ----------------

struct MlpP {
    const float *b1, *g1, *be1, *m1, *v1;
    const float *b2, *g2, *be2, *m2, *v2;
};

static void run_mlp(hipStream_t stream, const ushort_t* inB, int M,
                    const ushort_t* wh, int mlp,
                    ushort_t* tB, int CH,
                    const MlpP& W, ushort_t* outB, int relu2,
                    const float* vnadd, const int* batch) {
    const ushort_t* w1 = wh + (size_t)mlp * WPER;
    const ushort_t* w2 = w1 + NP1 * KP1;
    for (int c0 = 0; c0 < M; c0 += CH) {
        int Mc = (M - c0 < CH) ? (M - c0) : CH;
        int mb = cdiv(Mc, BMg);
        int mbp = cdiv(mb, 8) * 8;
        {
            int nb = NP1 / BNg;   // 5
            gemm_as<<<nb * mbp, 256, 0, stream>>>(
                inB + (size_t)c0 * KP1, KP1, w1,
                W.b1, W.g1, W.be1, W.m1, W.v1,
                Mc, 2 * EMBD, 1, nb, mb,
                nullptr, nullptr,
                nullptr, 0, tB, KP2);
        }
        {
            int nb = NP2 / BNg;   // 3
            gemm_as<<<nb * mbp, 256, 0, stream>>>(
                tB, KP2, w2,
                W.b2, W.g2, W.be2, W.m2, W.v2,
                Mc, EMBD, relu2, nb, mb,
                vnadd, vnadd ? (batch + c0) : nullptr,
                nullptr, 0, outB + (size_t)c0 * KP1, KP1);
        }
    }
}

// ---------------- entry ----------------

extern "C" void kernel_launch(void* const* d_in, const int* in_sizes, int n_in,
                              void* d_out, int out_size, void* d_ws, size_t ws_size,
                              hipStream_t stream) {
    const int*   x        = (const int*)d_in[0];
    const int*   ei       = (const int*)d_in[1];
    const int*   ea       = (const int*)d_in[2];
    const int*   batch    = (const int*)d_in[3];
    const float* atom_emb = (const float*)d_in[4];
    const float* bond_emb = (const float*)d_in[5];
    const float* vn_emb   = (const float*)d_in[6];
    const float* gin_eps  = (const float*)d_in[7];
    const float* gin_W1   = (const float*)d_in[8];
    const float* gin_b1   = (const float*)d_in[9];
    const float* gin_bn1g = (const float*)d_in[10];
    const float* gin_bn1b = (const float*)d_in[11];
    const float* gin_bn1m = (const float*)d_in[12];
    const float* gin_bn1v = (const float*)d_in[13];
    const float* gin_W2   = (const float*)d_in[14];
    const float* gin_b2   = (const float*)d_in[15];
    const float* bn_g     = (const float*)d_in[16];
    const float* bn_b     = (const float*)d_in[17];
    const float* bn_m     = (const float*)d_in[18];
    const float* bn_v     = (const float*)d_in[19];
    const float* vn_W1    = (const float*)d_in[20];
    const float* vn_b1    = (const float*)d_in[21];
    const float* vn_bn1g  = (const float*)d_in[22];
    const float* vn_bn1b  = (const float*)d_in[23];
    const float* vn_bn1m  = (const float*)d_in[24];
    const float* vn_bn1v  = (const float*)d_in[25];
    const float* vn_W2    = (const float*)d_in[26];
    const float* vn_b2    = (const float*)d_in[27];
    const float* vn_bn2g  = (const float*)d_in[28];
    const float* vn_bn2b  = (const float*)d_in[29];
    const float* vn_bn2m  = (const float*)d_in[30];
    const float* vn_bn2v  = (const float*)d_in[31];

    const int N = in_sizes[3];
    const int E = in_sizes[1] / 2;
    const int NB = cdiv(N, 1024);

    // ---- workspace layout (bytes); fixed ~147 MB of the ~256 MiB budget ----
    char* base = (char*)d_ws;
    size_t off = 0;
    ushort_t* hbuf = (ushort_t*)(base + off); off += (size_t)N * KP1 * 2;    // 64 MB
    ushort_t* aggB = (ushort_t*)(base + off); off += (size_t)N * KP1 * 2;    // 64 MB
    float* vnbuf   = (float*)(base + off);    off += (size_t)GG * EMBD * 4;  // 4.9 MB
    int*   starts  = (int*)(base + off);      off += 4104 * 4;
    int*   cnt     = (int*)(base + off);      off += (size_t)N * 4;
    int*   cursor  = (int*)(base + off);      off += (size_t)N * 4;
    int*   estart  = (int*)(base + off);      off += ((size_t)N + 8) * 4;
    int*   bsum    = (int*)(base + off);      off += 1032 * 4;
    int2*  epack   = (int2*)(base + off);     off += (size_t)E * 8;          // 2 MB
    float* ebsum   = (float*)(base + off);    off += (size_t)512 * EMBD * 4; // 0.6 MB
    ushort_t* whA  = (ushort_t*)(base + off); off += (size_t)9 * WPER * 2;   // 8.1 MB
    ushort_t* vnaB = (ushort_t*)(base + off); off += (size_t)GG * KP1 * 2;   // 2.6 MB
    off = (off + 255) & ~(size_t)255;

    // adaptive chunk for tB: KP2*2 = 1280 B per row; balance if 2 chunks
    size_t avail = (ws_size > off) ? ws_size - off : 0;
    int CH = (int)(avail / (KP2 * 2));
    CH &= ~255;
    if (CH > N) CH = (N + 255) & ~255;
    else if (CH >= (N + 1) / 2) CH = (((N + 1) / 2) + 255) & ~255;   // 2 balanced chunks
    if (CH < 2048) CH = 2048;  // last resort
    ushort_t* tB = (ushort_t*)(base + off);

    const int BLK = 256;
    int ne4 = N * 75;

    // ---- one-time init ----
    find_starts<<<cdiv(GG + 1, BLK), BLK, 0, stream>>>(batch, starts, N);
    atom_encode_bf<<<cdiv(ne4, BLK), BLK, 0, stream>>>(x, atom_emb, vn_emb, hbuf, N);
    init_vn4<<<cdiv(GG * 75, BLK), BLK, 0, stream>>>(vn_emb, vnbuf);
    bond_combo<<<cdiv(512 * EMBD, BLK), BLK, 0, stream>>>(bond_emb, ebsum);
    conv_all<<<cdiv(9 * WPER, BLK), BLK, 0, stream>>>(gin_W1, gin_W2, vn_W1, vn_W2, whA);
    hipMemsetAsync(cnt, 0, (size_t)N * 4, stream);
    hipMemsetAsync(vnaB, 0, (size_t)GG * KP1 * 2, stream);  // zero pad cols (ws re-poisoned each call)
    ecount<<<cdiv(E, BLK), BLK, 0, stream>>>(ei, cnt, E);
    scan_part<<<NB, 256, 0, stream>>>(cnt, bsum, N);
    scan_top<<<1, 1024, 0, stream>>>(bsum, NB);
    scan_final<<<NB, 256, 0, stream>>>(cnt, bsum, estart, cursor, N, E);
    escatter<<<cdiv(E, BLK), BLK, 0, stream>>>(ei, ea, cursor, epack, E);

    for (int l = 0; l < NLAY; ++l) {
        int last = (l == NLAY - 1);

        if (!last) {
            // vnaB = pool(h) + vn_l  (h already contains vn_l)
            pool_only<<<GG, 320, 0, stream>>>(hbuf, vnbuf, starts, vnaB);
            // vn_{l+1} = relu(bn2(mlp(vnaB))) -> vnbuf (fp32)
            const ushort_t* w1 = whA + (size_t)(NLAY + l) * WPER;
            const ushort_t* w2 = w1 + NP1 * KP1;
            int mb = cdiv(GG, BMg), mbp = cdiv(mb, 8) * 8;
            gemm_as<<<(NP1 / BNg) * mbp, 256, 0, stream>>>(
                vnaB, KP1, w1,
                vn_b1 + (size_t)l * 2 * EMBD, vn_bn1g + (size_t)l * 2 * EMBD,
                vn_bn1b + (size_t)l * 2 * EMBD, vn_bn1m + (size_t)l * 2 * EMBD,
                vn_bn1v + (size_t)l * 2 * EMBD,
                GG, 2 * EMBD, 1, NP1 / BNg, mb,
                nullptr, nullptr,
                nullptr, 0, tB, KP2);
            gemm_as<<<(NP2 / BNg) * mbp, 256, 0, stream>>>(
                tB, KP2, w2,
                vn_b2 + (size_t)l * EMBD, vn_bn2g + (size_t)l * EMBD,
                vn_bn2b + (size_t)l * EMBD, vn_bn2m + (size_t)l * EMBD,
                vn_bn2v + (size_t)l * EMBD,
                GG, EMBD, 1, NP2 / BNg, mb,
                nullptr, nullptr,
                vnbuf, EMBD, nullptr, 0);
        }

        // aggB = bf16( (1+eps)h + sum relu(h[src]+bond) )
        aggregate<<<cdiv(N, NPB), NPB * 80, 0, stream>>>(
            hbuf, ebsum, estart, epack, gin_eps + l, aggB, N);

        // h = bn(mlp(aggB)) (+relu, +vn_{l+1} unless last)
        MlpP Wn = { gin_b1 + (size_t)l * 2 * EMBD,
                    gin_bn1g + (size_t)l * 2 * EMBD, gin_bn1b + (size_t)l * 2 * EMBD,
                    gin_bn1m + (size_t)l * 2 * EMBD, gin_bn1v + (size_t)l * 2 * EMBD,
                    gin_b2 + (size_t)l * EMBD,
                    bn_g + (size_t)l * EMBD, bn_b + (size_t)l * EMBD,
                    bn_m + (size_t)l * EMBD, bn_v + (size_t)l * EMBD };
        run_mlp(stream, aggB, N, whA, l, tB, CH, Wn, hbuf, last ? 0 : 1,
                last ? nullptr : vnbuf, batch);
    }

    pool_mean<<<GG, 320, 0, stream>>>(hbuf, starts, (float*)d_out);
}

// Round 12
// 1934.121 us; speedup vs baseline: 1.1674x; 1.1047x over previous
//
#include <hip/hip_runtime.h>
#include <hip/hip_bf16.h>

#define EMBD 300
#define GG   4096
#define NLAY 5
#define KP1  320   // padded K for EMB=300 inputs (also h row stride)
#define KP2  640   // padded K for 2*EMB=600 inputs
#define NP1  640   // padded out-cols for 600
#define NP2  384   // padded out-cols for 300 (3 x 128)
#define WPER (NP1*KP1 + NP2*KP2)   // 450560 elems per MLP weight set

typedef unsigned short ushort_t;
typedef short short8 __attribute__((ext_vector_type(8)));
typedef short short4v __attribute__((ext_vector_type(4)));
typedef float f32x4 __attribute__((ext_vector_type(4)));

static inline int cdiv(int a, int b) { return (a + b - 1) / b; }

// ---------------- helpers ----------------

__device__ inline void dma16(const ushort_t* g, ushort_t* l) {
    __builtin_amdgcn_global_load_lds(
        (const __attribute__((address_space(1))) unsigned int*)g,
        (__attribute__((address_space(3))) unsigned int*)l, 16, 0, 0);
}

__device__ inline ushort_t bf16_of(float v) {
    union { __hip_bfloat16 b; ushort_t u; } c;
    c.b = __float2bfloat16(v);
    return c.u;
}

__device__ inline float bf2f(ushort_t u) {
    union { unsigned int i; float f; } c;
    c.i = ((unsigned int)u) << 16;
    return c.f;
}

// ---------------- init kernels ----------------

// atom encode -> h bf16 [N][KP1]
__global__ void atom_encode_bf(const int* __restrict__ x, const float* __restrict__ aemb,
                               ushort_t* __restrict__ h, int N) {
    int i = blockIdx.x * blockDim.x + threadIdx.x;
    int total = N * 75;
    if (i >= total) return;
    int n = i / 75, d4 = i - n * 75;
    const int* xr = x + n * 9;
    float4 s = make_float4(0.f, 0.f, 0.f, 0.f);
    const float4* a4 = (const float4*)aemb;
#pragma unroll
    for (int f = 0; f < 9; ++f) {
        float4 v = a4[(size_t)((f << 7) + xr[f]) * 75 + d4];
        s.x += v.x; s.y += v.y; s.z += v.z; s.w += v.w;
    }
    short4v o;
    o[0] = (short)bf16_of(s.x); o[1] = (short)bf16_of(s.y);
    o[2] = (short)bf16_of(s.z); o[3] = (short)bf16_of(s.w);
    *(short4v*)(h + (size_t)n * KP1 + d4 * 4) = o;
}

__global__ void init_vn4(const float* __restrict__ vn_emb, float* __restrict__ vn) {
    int i = blockIdx.x * blockDim.x + threadIdx.x;
    if (i >= GG * 75) return;
    ((float4*)vn)[i] = ((const float4*)vn_emb)[i % 75];
}

__global__ void find_starts(const int* __restrict__ batch, int* __restrict__ starts, int N) {
    int g = blockIdx.x * blockDim.x + threadIdx.x;
    if (g > GG) return;
    int lo = 0, hi = N;
    while (lo < hi) {
        int mid = (lo + hi) >> 1;
        if (batch[mid] < g) lo = mid + 1; else hi = mid;
    }
    starts[g] = lo;
}

// bond combo table: ebsum[c][d], c=(a0<<6)|(a1<<3)|a2
__global__ void bond_combo(const float* __restrict__ bemb, float* __restrict__ ebsum) {
    int i = blockIdx.x * blockDim.x + threadIdx.x;
    if (i >= 512 * EMBD) return;
    int c = i / EMBD, d = i - c * EMBD;
    int a0 = c >> 6, a1 = (c >> 3) & 7, a2 = c & 7;
    ebsum[i] = bemb[a0 * EMBD + d] + bemb[(8 + a1) * EMBD + d] + bemb[(16 + a2) * EMBD + d];
}

// convert all 9 MLP weight sets into transposed single-bf16 planes
__global__ void conv_all(const float* __restrict__ gW1, const float* __restrict__ gW2,
                         const float* __restrict__ vW1, const float* __restrict__ vW2,
                         ushort_t* __restrict__ wh) {
    int i = blockIdx.x * blockDim.x + threadIdx.x;
    int total = WPER * 9;
    if (i >= total) return;
    int mlp = i / WPER, r = i - mlp * WPER;
    const float *W1, *W2;
    if (mlp < NLAY) {
        W1 = gW1 + (size_t)mlp * EMBD * 2 * EMBD;
        W2 = gW2 + (size_t)mlp * 2 * EMBD * EMBD;
    } else {
        int l = mlp - NLAY;
        W1 = vW1 + (size_t)l * EMBD * 2 * EMBD;
        W2 = vW2 + (size_t)l * 2 * EMBD * EMBD;
    }
    float v;
    if (r < NP1 * KP1) {
        int n = r / KP1, k = r - n * KP1;
        v = (n < 2 * EMBD && k < EMBD) ? W1[(size_t)k * (2 * EMBD) + n] : 0.f;
    } else {
        int r2 = r - NP1 * KP1;
        int n = r2 / KP2, k = r2 - n * KP2;
        v = (n < EMBD && k < 2 * EMBD) ? W2[(size_t)k * EMBD + n] : 0.f;
    }
    wh[i] = bf16_of(v);
}

// ---------------- edge bucket sort ----------------

__global__ void ecount(const int* __restrict__ ei, int* __restrict__ cnt, int E) {
    int e = blockIdx.x * blockDim.x + threadIdx.x;
    if (e >= E) return;
    atomicAdd(&cnt[ei[E + e]], 1);
}

__global__ void scan_part(const int* __restrict__ cnt, int* __restrict__ bsum, int N) {
    __shared__ int sh[256];
    int b = blockIdx.x, t = threadIdx.x;
    int base = b * 1024;
    int s = 0;
    for (int j = t; j < 1024; j += 256) {
        int idx = base + j;
        if (idx < N) s += cnt[idx];
    }
    sh[t] = s;
    __syncthreads();
    for (int d = 128; d > 0; d >>= 1) {
        if (t < d) sh[t] += sh[t + d];
        __syncthreads();
    }
    if (t == 0) bsum[b] = sh[0];
}

__global__ void scan_top(int* __restrict__ bsum, int nb) {
    __shared__ int sh[1024];
    int t = threadIdx.x;
    int v = (t < nb) ? bsum[t] : 0;
    sh[t] = v;
    __syncthreads();
    for (int d = 1; d < 1024; d <<= 1) {
        int u = (t >= d) ? sh[t - d] : 0;
        __syncthreads();
        sh[t] += u;
        __syncthreads();
    }
    if (t < nb) bsum[t] = sh[t] - v;  // exclusive
}

__global__ void scan_final(const int* __restrict__ cnt, const int* __restrict__ bsum,
                           int* __restrict__ estart, int* __restrict__ cursor, int N, int E) {
    __shared__ int sh[256];
    int b = blockIdx.x, t = threadIdx.x;
    int base = b * 1024 + t * 4;
    int c[4];
    int s = 0;
#pragma unroll
    for (int j = 0; j < 4; ++j) {
        int idx = base + j;
        c[j] = (idx < N) ? cnt[idx] : 0;
        s += c[j];
    }
    sh[t] = s;
    __syncthreads();
    for (int d = 1; d < 256; d <<= 1) {
        int u = (t >= d) ? sh[t - d] : 0;
        __syncthreads();
        sh[t] += u;
        __syncthreads();
    }
    int run = sh[t] - s + bsum[b];
#pragma unroll
    for (int j = 0; j < 4; ++j) {
        int idx = base + j;
        if (idx < N) { estart[idx] = run; cursor[idx] = run; run += c[j]; }
    }
    if (b == 0 && t == 0) estart[N] = E;
}

__global__ void escatter(const int* __restrict__ ei, const int* __restrict__ ea,
                         int* __restrict__ cursor, int2* __restrict__ epack, int E) {
    int e = blockIdx.x * blockDim.x + threadIdx.x;
    if (e >= E) return;
    int c = ei[E + e];
    int p = atomicAdd(&cursor[c], 1);
    epack[p] = make_int2(ei[e], (ea[3 * e] << 6) | (ea[3 * e + 1] << 3) | ea[3 * e + 2]);
}

// ---------------- fused per-layer elementwise (h is bf16 [N][KP1]) ----------------

// non-last: h[n] += vn[g] in place (bf16); vnaB[g] = bf16(segment_sum(h_new) + vn[g])
__global__ void pool_prep(ushort_t* __restrict__ h, const float* __restrict__ vn,
                          const int* __restrict__ starts, ushort_t* __restrict__ vnaB) {
    int g = blockIdx.x;
    int t = threadIdx.x;   // 320
    if (t >= EMBD) return;
    float vng = vn[(size_t)g * EMBD + t];
    int s0 = starts[g], s1 = starts[g + 1];
    float s = 0.f;
    for (int n = s0; n < s1; ++n) {
        size_t idx = (size_t)n * KP1 + t;
        float v = bf2f(h[idx]) + vng;
        h[idx] = bf16_of(v);
        s += v;
    }
    vnaB[(size_t)g * KP1 + t] = bf16_of(s + vng);
}

__global__ void prep_vn(ushort_t* __restrict__ h, const float* __restrict__ vn,
                        const int* __restrict__ batch, int N) {
    int i = blockIdx.x * blockDim.x + threadIdx.x;
    int total = N * 75;
    if (i >= total) return;
    int n = i / 75, d4 = i - n * 75;
    float4 vv = ((const float4*)vn)[(size_t)batch[n] * 75 + d4];
    short4v hv = *(short4v*)(h + (size_t)n * KP1 + d4 * 4);
    short4v o;
    o[0] = (short)bf16_of(bf2f((ushort_t)hv[0]) + vv.x);
    o[1] = (short)bf16_of(bf2f((ushort_t)hv[1]) + vv.y);
    o[2] = (short)bf16_of(bf2f((ushort_t)hv[2]) + vv.z);
    o[3] = (short)bf16_of(bf2f((ushort_t)hv[3]) + vv.w);
    *(short4v*)(h + (size_t)n * KP1 + d4 * 4) = o;
}

__global__ void pool_mean(const ushort_t* __restrict__ h, const int* __restrict__ starts,
                          float* __restrict__ out) {
    int g = blockIdx.x;
    int t = threadIdx.x;
    if (t >= EMBD) return;
    int s0 = starts[g], s1 = starts[g + 1];
    float s = 0.f;
    for (int n = s0; n < s1; ++n) s += bf2f(h[(size_t)n * KP1 + t]);
    float cnt = (float)(s1 - s0);
    out[(size_t)g * EMBD + t] = s / fmaxf(cnt, 1.0f);
}

// ---------------- fused aggregate ----------------
#define NPB 4   // nodes per block; blockDim = NPB*80 = 320

__global__ void aggregate(const ushort_t* __restrict__ h, const float* __restrict__ ebsum,
                          const int* __restrict__ estart, const int2* __restrict__ epack,
                          const float* __restrict__ epsp,
                          ushort_t* __restrict__ aggB, int N) {
    int n = blockIdx.x * NPB + threadIdx.x / 80;
    int slot = threadIdx.x % 80;
    if (n >= N) return;
    float4 acc = make_float4(0.f, 0.f, 0.f, 0.f);
    if (slot < 75) {
        const float4* b4 = (const float4*)ebsum;
        float ce = 1.0f + *epsp;
        short4v hv = *(const short4v*)(h + (size_t)n * KP1 + slot * 4);
        acc.x = ce * bf2f((ushort_t)hv[0]);
        acc.y = ce * bf2f((ushort_t)hv[1]);
        acc.z = ce * bf2f((ushort_t)hv[2]);
        acc.w = ce * bf2f((ushort_t)hv[3]);
        int p0 = estart[n], p1 = estart[n + 1];
        for (int p = p0; p < p1; ++p) {
            int2 ep = epack[p];
            short4v xv = *(const short4v*)(h + (size_t)ep.x * KP1 + slot * 4);
            float4 ev = b4[(size_t)ep.y * 75 + slot];
            acc.x += fmaxf(bf2f((ushort_t)xv[0]) + ev.x, 0.f);
            acc.y += fmaxf(bf2f((ushort_t)xv[1]) + ev.y, 0.f);
            acc.z += fmaxf(bf2f((ushort_t)xv[2]) + ev.z, 0.f);
            acc.w += fmaxf(bf2f((ushort_t)xv[3]) + ev.w, 0.f);
        }
    }
    short4v bv4;
    bv4[0] = (short)bf16_of(acc.x);
    bv4[1] = (short)bf16_of(acc.y);
    bv4[2] = (short)bf16_of(acc.z);
    bv4[3] = (short)bf16_of(acc.w);
    *(short4v*)(aggB + (size_t)n * KP1 + slot * 4) = bv4;
}

// ---------------- MFMA GEMM: single-bf16 A and B, 128x128 tile, 2-stage LDS, XCD swizzle ----------------
#define BMg 128
#define BNg 128

__global__ __launch_bounds__(256) void gemm_as(
    const ushort_t* __restrict__ A, int KP,
    const ushort_t* __restrict__ B,
    const float* __restrict__ bias, const float* __restrict__ gg,
    const float* __restrict__ bb, const float* __restrict__ bm,
    const float* __restrict__ bv,
    int Mc, int NnReal, int relu, int nb, int mb,
    float* __restrict__ outF, int ldF,
    ushort_t* __restrict__ outB, int ldP)
{
    __shared__ ushort_t sA[2][BMg * 32];   // 2 x 8 KB
    __shared__ ushort_t sB[2][BNg * 32];   // 2 x 8 KB  (32 KB total -> 5 blocks/CU)

    // XCD-aware swizzle: same m-strip lands consecutively on one XCD
    int id = blockIdx.x;
    int hi = id / (8 * nb);
    int rem = id - hi * 8 * nb;
    int xcd = rem & 7;
    int nblk = rem >> 3;
    int mblk = hi * 8 + xcd;
    if (mblk >= mb) return;

    const int tid = threadIdx.x;
    const int lane = tid & 63;
    const int w = tid >> 6;
    const int m0 = mblk * BMg;
    const int n0 = nblk * BNg;
    const int wm = (w & 1) * 64;
    const int wn = (w >> 1) * 64;

    const ushort_t* gA[2];
    const ushort_t* gB[2];
    int lbase[2];
#pragma unroll
    for (int i = 0; i < 2; ++i) {
        int s = tid + 256 * i;
        int m = s >> 2, qp = s & 3;
        int q = (qp - (m >> 1)) & 3;
        int msrc = (m0 + m < Mc) ? (m0 + m) : (Mc - 1);
        gA[i] = A + (size_t)msrc * KP + 8 * q;
        gB[i] = B + (size_t)(n0 + m) * KP + 8 * q;   // B rows fully padded
        lbase[i] = (w * 64 + 256 * i) * 8;
    }

    f32x4 acc[4][4];
#pragma unroll
    for (int a = 0; a < 4; ++a)
#pragma unroll
        for (int b = 0; b < 4; ++b) acc[a][b] = (f32x4)(0.f);

    const int q = lane >> 4;
    const int c16 = lane & 15;
    const int kt = KP >> 5;

    // prefetch tile 0 -> stage 0
#pragma unroll
    for (int i = 0; i < 2; ++i) {
        dma16(gA[i], sA[0] + lbase[i]); gA[i] += 32;
        dma16(gB[i], sB[0] + lbase[i]); gB[i] += 32;
    }
    __syncthreads();

    for (int t = 0; t < kt; ++t) {
        int cur = t & 1, nxt = cur ^ 1;
        if (t + 1 < kt) {
#pragma unroll
            for (int i = 0; i < 2; ++i) {
                dma16(gA[i], sA[nxt] + lbase[i]); gA[i] += 32;
                dma16(gB[i], sB[nxt] + lbase[i]); gB[i] += 32;
            }
        }
        short8 av[4], bhv[4];
#pragma unroll
        for (int tt = 0; tt < 4; ++tt) {
            int m = wm + tt * 16 + c16;
            int q2 = (q + (m >> 1)) & 3;
            av[tt] = *(const short8*)(sA[cur] + m * 32 + q2 * 8);
        }
#pragma unroll
        for (int uu = 0; uu < 4; ++uu) {
            int n = wn + uu * 16 + c16;
            int q2 = (q + (n >> 1)) & 3;
            bhv[uu] = *(const short8*)(sB[cur] + n * 32 + q2 * 8);
        }
#pragma unroll
        for (int tt = 0; tt < 4; ++tt)
#pragma unroll
            for (int uu = 0; uu < 4; ++uu)
                acc[tt][uu] = __builtin_amdgcn_mfma_f32_16x16x32_bf16(av[tt], bhv[uu], acc[tt][uu], 0, 0, 0);
        __syncthreads();
    }

    // epilogue: C/D layout col=lane&15, row=q*4+r
#pragma unroll
    for (int uu = 0; uu < 4; ++uu) {
        int gn = n0 + wn + uu * 16 + c16;
        float sc = 0.f, sh = 0.f;
        if (gn < NnReal) {
            sc = gg[gn] * rsqrtf(bv[gn] + 1e-5f);
            sh = bb[gn] + (bias[gn] - bm[gn]) * sc;
        }
#pragma unroll
        for (int tt = 0; tt < 4; ++tt) {
            int rbase = m0 + wm + tt * 16 + q * 4;
#pragma unroll
            for (int r = 0; r < 4; ++r) {
                int gm = rbase + r;
                if (gm >= Mc) continue;
                float y = acc[tt][uu][r] * sc + sh;
                if (relu) y = fmaxf(y, 0.f);
                if (outF) {
                    if (gn < NnReal) outF[(size_t)gm * ldF + gn] = y;
                } else {
                    if (gn < ldP) outB[(size_t)gm * ldP + gn] = bf16_of(y);
                }
            }
        }
    }
}

// ---------------- host-side MLP ----------------

struct MlpP {
    const float *b1, *g1, *be1, *m1, *v1;
    const float *b2, *g2, *be2, *m2, *v2;
};

static void run_mlp(hipStream_t stream, const ushort_t* inB, int M,
                    const ushort_t* wh, int mlp,
                    ushort_t* tB, int CH,
                    const MlpP& W, ushort_t* outB, int relu2) {
    const ushort_t* w1 = wh + (size_t)mlp * WPER;
    const ushort_t* w2 = w1 + NP1 * KP1;
    for (int c0 = 0; c0 < M; c0 += CH) {
        int Mc = (M - c0 < CH) ? (M - c0) : CH;
        int mb = cdiv(Mc, BMg);
        int mbp = cdiv(mb, 8) * 8;
        {
            int nb = NP1 / BNg;   // 5
            gemm_as<<<nb * mbp, 256, 0, stream>>>(
                inB + (size_t)c0 * KP1, KP1, w1,
                W.b1, W.g1, W.be1, W.m1, W.v1,
                Mc, 2 * EMBD, 1, nb, mb,
                nullptr, 0, tB, KP2);
        }
        {
            int nb = NP2 / BNg;   // 3
            gemm_as<<<nb * mbp, 256, 0, stream>>>(
                tB, KP2, w2,
                W.b2, W.g2, W.be2, W.m2, W.v2,
                Mc, EMBD, relu2, nb, mb,
                nullptr, 0, outB + (size_t)c0 * KP1, KP1);
        }
    }
}

// ---------------- entry ----------------

extern "C" void kernel_launch(void* const* d_in, const int* in_sizes, int n_in,
                              void* d_out, int out_size, void* d_ws, size_t ws_size,
                              hipStream_t stream) {
    const int*   x        = (const int*)d_in[0];
    const int*   ei       = (const int*)d_in[1];
    const int*   ea       = (const int*)d_in[2];
    const int*   batch    = (const int*)d_in[3];
    const float* atom_emb = (const float*)d_in[4];
    const float* bond_emb = (const float*)d_in[5];
    const float* vn_emb   = (const float*)d_in[6];
    const float* gin_eps  = (const float*)d_in[7];
    const float* gin_W1   = (const float*)d_in[8];
    const float* gin_b1   = (const float*)d_in[9];
    const float* gin_bn1g = (const float*)d_in[10];
    const float* gin_bn1b = (const float*)d_in[11];
    const float* gin_bn1m = (const float*)d_in[12];
    const float* gin_bn1v = (const float*)d_in[13];
    const float* gin_W2   = (const float*)d_in[14];
    const float* gin_b2   = (const float*)d_in[15];
    const float* bn_g     = (const float*)d_in[16];
    const float* bn_b     = (const float*)d_in[17];
    const float* bn_m     = (const float*)d_in[18];
    const float* bn_v     = (const float*)d_in[19];
    const float* vn_W1    = (const float*)d_in[20];
    const float* vn_b1    = (const float*)d_in[21];
    const float* vn_bn1g  = (const float*)d_in[22];
    const float* vn_bn1b  = (const float*)d_in[23];
    const float* vn_bn1m  = (const float*)d_in[24];
    const float* vn_bn1v  = (const float*)d_in[25];
    const float* vn_W2    = (const float*)d_in[26];
    const float* vn_b2    = (const float*)d_in[27];
    const float* vn_bn2g  = (const float*)d_in[28];
    const float* vn_bn2b  = (const float*)d_in[29];
    const float* vn_bn2m  = (const float*)d_in[30];
    const float* vn_bn2v  = (const float*)d_in[31];

    const int N = in_sizes[3];
    const int E = in_sizes[1] / 2;
    const int NB = cdiv(N, 1024);

    // ---- workspace layout (bytes); fixed ~147 MB of the ~256 MiB budget ----
    char* base = (char*)d_ws;
    size_t off = 0;
    ushort_t* hbuf = (ushort_t*)(base + off); off += (size_t)N * KP1 * 2;    // 64 MB
    ushort_t* aggB = (ushort_t*)(base + off); off += (size_t)N * KP1 * 2;    // 64 MB
    float* vnbuf   = (float*)(base + off);    off += (size_t)GG * EMBD * 4;  // 4.9 MB
    int*   starts  = (int*)(base + off);      off += 4104 * 4;
    int*   cnt     = (int*)(base + off);      off += (size_t)N * 4;
    int*   cursor  = (int*)(base + off);      off += (size_t)N * 4;
    int*   estart  = (int*)(base + off);      off += ((size_t)N + 8) * 4;
    int*   bsum    = (int*)(base + off);      off += 1032 * 4;
    int2*  epack   = (int2*)(base + off);     off += (size_t)E * 8;          // 2 MB
    float* ebsum   = (float*)(base + off);    off += (size_t)512 * EMBD * 4; // 0.6 MB
    ushort_t* whA  = (ushort_t*)(base + off); off += (size_t)9 * WPER * 2;   // 8.1 MB
    ushort_t* vnaB = (ushort_t*)(base + off); off += (size_t)GG * KP1 * 2;   // 2.6 MB
    off = (off + 255) & ~(size_t)255;

    // adaptive chunk for tB: KP2*2 = 1280 B per row; balance if 2 chunks
    size_t avail = (ws_size > off) ? ws_size - off : 0;
    int CH = (int)(avail / (KP2 * 2));
    CH &= ~255;
    if (CH > N) CH = (N + 255) & ~255;
    else if (CH >= (N + 1) / 2) CH = (((N + 1) / 2) + 255) & ~255;   // 2 balanced chunks
    if (CH < 2048) CH = 2048;  // last resort
    ushort_t* tB = (ushort_t*)(base + off);

    const int BLK = 256;
    int ne4 = N * 75;

    // ---- one-time init ----
    find_starts<<<cdiv(GG + 1, BLK), BLK, 0, stream>>>(batch, starts, N);
    atom_encode_bf<<<cdiv(ne4, BLK), BLK, 0, stream>>>(x, atom_emb, hbuf, N);
    init_vn4<<<cdiv(GG * 75, BLK), BLK, 0, stream>>>(vn_emb, vnbuf);
    bond_combo<<<cdiv(512 * EMBD, BLK), BLK, 0, stream>>>(bond_emb, ebsum);
    conv_all<<<cdiv(9 * WPER, BLK), BLK, 0, stream>>>(gin_W1, gin_W2, vn_W1, vn_W2, whA);
    hipMemsetAsync(cnt, 0, (size_t)N * 4, stream);
    hipMemsetAsync(vnaB, 0, (size_t)GG * KP1 * 2, stream);
    ecount<<<cdiv(E, BLK), BLK, 0, stream>>>(ei, cnt, E);
    scan_part<<<NB, 256, 0, stream>>>(cnt, bsum, N);
    scan_top<<<1, 1024, 0, stream>>>(bsum, NB);
    scan_final<<<NB, 256, 0, stream>>>(cnt, bsum, estart, cursor, N, E);
    escatter<<<cdiv(E, BLK), BLK, 0, stream>>>(ei, ea, cursor, epack, E);

    for (int l = 0; l < NLAY; ++l) {
        int last = (l == NLAY - 1);

        if (!last)
            pool_prep<<<GG, 320, 0, stream>>>(hbuf, vnbuf, starts, vnaB);
        else
            prep_vn<<<cdiv(ne4, BLK), BLK, 0, stream>>>(hbuf, vnbuf, batch, N);

        aggregate<<<cdiv(N, NPB), NPB * 80, 0, stream>>>(
            hbuf, ebsum, estart, epack, gin_eps + l, aggB, N);

        MlpP Wn = { gin_b1 + (size_t)l * 2 * EMBD,
                    gin_bn1g + (size_t)l * 2 * EMBD, gin_bn1b + (size_t)l * 2 * EMBD,
                    gin_bn1m + (size_t)l * 2 * EMBD, gin_bn1v + (size_t)l * 2 * EMBD,
                    gin_b2 + (size_t)l * EMBD,
                    bn_g + (size_t)l * EMBD, bn_b + (size_t)l * EMBD,
                    bn_m + (size_t)l * EMBD, bn_v + (size_t)l * EMBD };
        run_mlp(stream, aggB, N, whA, l, tB, CH, Wn, hbuf, last ? 0 : 1);

        if (!last) {
            MlpP Wv = { vn_b1 + (size_t)l * 2 * EMBD,
                        vn_bn1g + (size_t)l * 2 * EMBD, vn_bn1b + (size_t)l * 2 * EMBD,
                        vn_bn1m + (size_t)l * 2 * EMBD, vn_bn1v + (size_t)l * 2 * EMBD,
                        vn_b2 + (size_t)l * EMBD,
                        vn_bn2g + (size_t)l * EMBD, vn_bn2b + (size_t)l * EMBD,
                        vn_bn2m + (size_t)l * EMBD, vn_bn2v + (size_t)l * EMBD };
            const ushort_t* w1 = whA + (size_t)(NLAY + l) * WPER;
            const ushort_t* w2 = w1 + NP1 * KP1;
            int mb = cdiv(GG, BMg), mbp = cdiv(mb, 8) * 8;
            gemm_as<<<(NP1 / BNg) * mbp, 256, 0, stream>>>(
                vnaB, KP1, w1,
                vn_b1 + (size_t)l * 2 * EMBD, vn_bn1g + (size_t)l * 2 * EMBD,
                vn_bn1b + (size_t)l * 2 * EMBD, vn_bn1m + (size_t)l * 2 * EMBD,
                vn_bn1v + (size_t)l * 2 * EMBD,
                GG, 2 * EMBD, 1, NP1 / BNg, mb,
                nullptr, 0, tB, KP2);
            gemm_as<<<(NP2 / BNg) * mbp, 256, 0, stream>>>(
                tB, KP2, w2,
                vn_b2 + (size_t)l * EMBD, vn_bn2g + (size_t)l * EMBD,
                vn_bn2b + (size_t)l * EMBD, vn_bn2m + (size_t)l * EMBD,
                vn_bn2v + (size_t)l * EMBD,
                GG, EMBD, 1, NP2 / BNg, mb,
                vnbuf, EMBD, nullptr, 0);
        }
    }

    pool_mean<<<GG, 320, 0, stream>>>(hbuf, starts, (float*)d_out);
}

// Round 13
// 1748.835 us; speedup vs baseline: 1.2911x; 1.1059x over previous
//
#include <hip/hip_runtime.h>
#include <hip/hip_bf16.h>

#define EMBD 300
#define GG   4096
#define NLAY 5
#define KP1  320   // padded K for EMB=300 inputs (h / aggB row stride)
#define KP2  640   // W2 weight-plane K stride
#define KT2  608   // t-buffer row stride (19 x 32; trims one k-tile vs 640)
#define NP1  640   // padded out-cols for 600
#define NP2  384   // padded out-cols for 300 (3 x 128)
#define WPER (NP1*KP1 + NP2*KP2)   // 450560 elems per MLP weight set

typedef unsigned short ushort_t;
typedef short short8 __attribute__((ext_vector_type(8)));
typedef short short4v __attribute__((ext_vector_type(4)));
typedef float f32x4 __attribute__((ext_vector_type(4)));

static inline int cdiv(int a, int b) { return (a + b - 1) / b; }

// ---------------- helpers ----------------

__device__ inline void dma16(const ushort_t* g, ushort_t* l) {
    __builtin_amdgcn_global_load_lds(
        (const __attribute__((address_space(1))) unsigned int*)g,
        (__attribute__((address_space(3))) unsigned int*)l, 16, 0, 0);
}

__device__ inline ushort_t bf16_of(float v) {
    union { __hip_bfloat16 b; ushort_t u; } c;
    c.b = __float2bfloat16(v);
    return c.u;
}

__device__ inline float bf2f(ushort_t u) {
    union { unsigned int i; float f; } c;
    c.i = ((unsigned int)u) << 16;
    return c.f;
}

// ---------------- init kernels ----------------

// atom encode -> h bf16 [N][KP1]
__global__ void atom_encode_bf(const int* __restrict__ x, const float* __restrict__ aemb,
                               ushort_t* __restrict__ h, int N) {
    int i = blockIdx.x * blockDim.x + threadIdx.x;
    int total = N * 75;
    if (i >= total) return;
    int n = i / 75, d4 = i - n * 75;
    const int* xr = x + n * 9;
    float4 s = make_float4(0.f, 0.f, 0.f, 0.f);
    const float4* a4 = (const float4*)aemb;
#pragma unroll
    for (int f = 0; f < 9; ++f) {
        float4 v = a4[(size_t)((f << 7) + xr[f]) * 75 + d4];
        s.x += v.x; s.y += v.y; s.z += v.z; s.w += v.w;
    }
    short4v o;
    o[0] = (short)bf16_of(s.x); o[1] = (short)bf16_of(s.y);
    o[2] = (short)bf16_of(s.z); o[3] = (short)bf16_of(s.w);
    *(short4v*)(h + (size_t)n * KP1 + d4 * 4) = o;
}

__global__ void init_vn4(const float* __restrict__ vn_emb, float* __restrict__ vn) {
    int i = blockIdx.x * blockDim.x + threadIdx.x;
    if (i >= GG * 75) return;
    ((float4*)vn)[i] = ((const float4*)vn_emb)[i % 75];
}

__global__ void find_starts(const int* __restrict__ batch, int* __restrict__ starts, int N) {
    int g = blockIdx.x * blockDim.x + threadIdx.x;
    if (g > GG) return;
    int lo = 0, hi = N;
    while (lo < hi) {
        int mid = (lo + hi) >> 1;
        if (batch[mid] < g) lo = mid + 1; else hi = mid;
    }
    starts[g] = lo;
}

// bond combo table: ebsum[c][d], c=(a0<<6)|(a1<<3)|a2
__global__ void bond_combo(const float* __restrict__ bemb, float* __restrict__ ebsum) {
    int i = blockIdx.x * blockDim.x + threadIdx.x;
    if (i >= 512 * EMBD) return;
    int c = i / EMBD, d = i - c * EMBD;
    int a0 = c >> 6, a1 = (c >> 3) & 7, a2 = c & 7;
    ebsum[i] = bemb[a0 * EMBD + d] + bemb[(8 + a1) * EMBD + d] + bemb[(16 + a2) * EMBD + d];
}

// convert all 9 MLP weight sets into transposed single-bf16 planes
__global__ void conv_all(const float* __restrict__ gW1, const float* __restrict__ gW2,
                         const float* __restrict__ vW1, const float* __restrict__ vW2,
                         ushort_t* __restrict__ wh) {
    int i = blockIdx.x * blockDim.x + threadIdx.x;
    int total = WPER * 9;
    if (i >= total) return;
    int mlp = i / WPER, r = i - mlp * WPER;
    const float *W1, *W2;
    if (mlp < NLAY) {
        W1 = gW1 + (size_t)mlp * EMBD * 2 * EMBD;
        W2 = gW2 + (size_t)mlp * 2 * EMBD * EMBD;
    } else {
        int l = mlp - NLAY;
        W1 = vW1 + (size_t)l * EMBD * 2 * EMBD;
        W2 = vW2 + (size_t)l * 2 * EMBD * EMBD;
    }
    float v;
    if (r < NP1 * KP1) {
        int n = r / KP1, k = r - n * KP1;
        v = (n < 2 * EMBD && k < EMBD) ? W1[(size_t)k * (2 * EMBD) + n] : 0.f;
    } else {
        int r2 = r - NP1 * KP1;
        int n = r2 / KP2, k = r2 - n * KP2;
        v = (n < EMBD && k < 2 * EMBD) ? W2[(size_t)k * EMBD + n] : 0.f;
    }
    wh[i] = bf16_of(v);
}

// ---------------- edge bucket sort ----------------

__global__ void ecount(const int* __restrict__ ei, int* __restrict__ cnt, int E) {
    int e = blockIdx.x * blockDim.x + threadIdx.x;
    if (e >= E) return;
    atomicAdd(&cnt[ei[E + e]], 1);
}

__global__ void scan_part(const int* __restrict__ cnt, int* __restrict__ bsum, int N) {
    __shared__ int sh[256];
    int b = blockIdx.x, t = threadIdx.x;
    int base = b * 1024;
    int s = 0;
    for (int j = t; j < 1024; j += 256) {
        int idx = base + j;
        if (idx < N) s += cnt[idx];
    }
    sh[t] = s;
    __syncthreads();
    for (int d = 128; d > 0; d >>= 1) {
        if (t < d) sh[t] += sh[t + d];
        __syncthreads();
    }
    if (t == 0) bsum[b] = sh[0];
}

__global__ void scan_top(int* __restrict__ bsum, int nb) {
    __shared__ int sh[1024];
    int t = threadIdx.x;
    int v = (t < nb) ? bsum[t] : 0;
    sh[t] = v;
    __syncthreads();
    for (int d = 1; d < 1024; d <<= 1) {
        int u = (t >= d) ? sh[t - d] : 0;
        __syncthreads();
        sh[t] += u;
        __syncthreads();
    }
    if (t < nb) bsum[t] = sh[t] - v;  // exclusive
}

// re-scan chunk with base; write estart; cursor aliases cnt (reads complete before writes)
__global__ void scan_final(int* __restrict__ cnt, const int* __restrict__ bsum,
                           int* __restrict__ estart, int* __restrict__ cursor, int N, int E) {
    __shared__ int sh[256];
    int b = blockIdx.x, t = threadIdx.x;
    int base = b * 1024 + t * 4;
    int c[4];
    int s = 0;
#pragma unroll
    for (int j = 0; j < 4; ++j) {
        int idx = base + j;
        c[j] = (idx < N) ? cnt[idx] : 0;
        s += c[j];
    }
    sh[t] = s;
    __syncthreads();
    for (int d = 1; d < 256; d <<= 1) {
        int u = (t >= d) ? sh[t - d] : 0;
        __syncthreads();
        sh[t] += u;
        __syncthreads();
    }
    int run = sh[t] - s + bsum[b];
#pragma unroll
    for (int j = 0; j < 4; ++j) {
        int idx = base + j;
        if (idx < N) { estart[idx] = run; cursor[idx] = run; run += c[j]; }
    }
    if (b == 0 && t == 0) estart[N] = E;
}

// scatter edges to dest buckets packed as (src<<9)|combo  (src<2^23, combo<512)
__global__ void escatter(const int* __restrict__ ei, const int* __restrict__ ea,
                         int* __restrict__ cursor, int* __restrict__ epack, int E) {
    int e = blockIdx.x * blockDim.x + threadIdx.x;
    if (e >= E) return;
    int c = ei[E + e];
    int p = atomicAdd(&cursor[c], 1);
    epack[p] = (ei[e] << 9) | (ea[3 * e] << 6) | (ea[3 * e + 1] << 3) | ea[3 * e + 2];
}

// ---------------- fused per-layer elementwise (h is bf16 [N][KP1]) ----------------

// non-last: h[n] += vn[g] in place; vnaB[g] = bf16(segment_sum(h_new) + vn[g]); vectorized 4 graphs/block
__global__ void pool_prep(ushort_t* __restrict__ h, const float* __restrict__ vn,
                          const int* __restrict__ starts, ushort_t* __restrict__ vnaB) {
    int g = blockIdx.x * 4 + threadIdx.x / 80;
    int slot = threadIdx.x % 80;
    if (g >= GG || slot >= 75) return;
    float4 vng = ((const float4*)vn)[(size_t)g * 75 + slot];
    int s0 = starts[g], s1 = starts[g + 1];
    float4 s = make_float4(0.f, 0.f, 0.f, 0.f);
    for (int n = s0; n < s1; ++n) {
        short4v* hp = (short4v*)(h + (size_t)n * KP1 + slot * 4);
        short4v hv = *hp;
        float v0 = bf2f((ushort_t)hv[0]) + vng.x;
        float v1 = bf2f((ushort_t)hv[1]) + vng.y;
        float v2 = bf2f((ushort_t)hv[2]) + vng.z;
        float v3 = bf2f((ushort_t)hv[3]) + vng.w;
        short4v o;
        o[0] = (short)bf16_of(v0); o[1] = (short)bf16_of(v1);
        o[2] = (short)bf16_of(v2); o[3] = (short)bf16_of(v3);
        *hp = o;
        s.x += v0; s.y += v1; s.z += v2; s.w += v3;
    }
    short4v o;
    o[0] = (short)bf16_of(s.x + vng.x); o[1] = (short)bf16_of(s.y + vng.y);
    o[2] = (short)bf16_of(s.z + vng.z); o[3] = (short)bf16_of(s.w + vng.w);
    *(short4v*)(vnaB + (size_t)g * KP1 + slot * 4) = o;
}

__global__ void prep_vn(ushort_t* __restrict__ h, const float* __restrict__ vn,
                        const int* __restrict__ batch, int N) {
    int i = blockIdx.x * blockDim.x + threadIdx.x;
    int total = N * 75;
    if (i >= total) return;
    int n = i / 75, d4 = i - n * 75;
    float4 vv = ((const float4*)vn)[(size_t)batch[n] * 75 + d4];
    short4v hv = *(short4v*)(h + (size_t)n * KP1 + d4 * 4);
    short4v o;
    o[0] = (short)bf16_of(bf2f((ushort_t)hv[0]) + vv.x);
    o[1] = (short)bf16_of(bf2f((ushort_t)hv[1]) + vv.y);
    o[2] = (short)bf16_of(bf2f((ushort_t)hv[2]) + vv.z);
    o[3] = (short)bf16_of(bf2f((ushort_t)hv[3]) + vv.w);
    *(short4v*)(h + (size_t)n * KP1 + d4 * 4) = o;
}

// vectorized mean pool, 4 graphs/block
__global__ void pool_mean(const ushort_t* __restrict__ h, const int* __restrict__ starts,
                          float* __restrict__ out) {
    int g = blockIdx.x * 4 + threadIdx.x / 80;
    int slot = threadIdx.x % 80;
    if (g >= GG || slot >= 75) return;
    int s0 = starts[g], s1 = starts[g + 1];
    float4 s = make_float4(0.f, 0.f, 0.f, 0.f);
    for (int n = s0; n < s1; ++n) {
        short4v hv = *(const short4v*)(h + (size_t)n * KP1 + slot * 4);
        s.x += bf2f((ushort_t)hv[0]);
        s.y += bf2f((ushort_t)hv[1]);
        s.z += bf2f((ushort_t)hv[2]);
        s.w += bf2f((ushort_t)hv[3]);
    }
    float inv = 1.0f / fmaxf((float)(s1 - s0), 1.0f);
    float4 o = make_float4(s.x * inv, s.y * inv, s.z * inv, s.w * inv);
    ((float4*)out)[(size_t)g * 75 + slot] = o;
}

// ---------------- fused aggregate (2-edge unroll, packed epack) ----------------
#define NPB 4   // nodes per block; blockDim = NPB*80 = 320

__global__ void aggregate(const ushort_t* __restrict__ h, const float* __restrict__ ebsum,
                          const int* __restrict__ estart, const int* __restrict__ epack,
                          const float* __restrict__ epsp,
                          ushort_t* __restrict__ aggB, int N) {
    int n = blockIdx.x * NPB + threadIdx.x / 80;
    int slot = threadIdx.x % 80;
    if (n >= N) return;
    float4 acc = make_float4(0.f, 0.f, 0.f, 0.f);
    if (slot < 75) {
        const float4* b4 = (const float4*)ebsum;
        float ce = 1.0f + *epsp;
        short4v hv = *(const short4v*)(h + (size_t)n * KP1 + slot * 4);
        acc.x = ce * bf2f((ushort_t)hv[0]);
        acc.y = ce * bf2f((ushort_t)hv[1]);
        acc.z = ce * bf2f((ushort_t)hv[2]);
        acc.w = ce * bf2f((ushort_t)hv[3]);
        int p0 = estart[n], p1 = estart[n + 1];
        int p = p0;
        for (; p + 2 <= p1; p += 2) {
            int e0 = epack[p], e1 = epack[p + 1];
            short4v xv0 = *(const short4v*)(h + (size_t)(e0 >> 9) * KP1 + slot * 4);
            short4v xv1 = *(const short4v*)(h + (size_t)(e1 >> 9) * KP1 + slot * 4);
            float4 ev0 = b4[(size_t)(e0 & 511) * 75 + slot];
            float4 ev1 = b4[(size_t)(e1 & 511) * 75 + slot];
            acc.x += fmaxf(bf2f((ushort_t)xv0[0]) + ev0.x, 0.f) + fmaxf(bf2f((ushort_t)xv1[0]) + ev1.x, 0.f);
            acc.y += fmaxf(bf2f((ushort_t)xv0[1]) + ev0.y, 0.f) + fmaxf(bf2f((ushort_t)xv1[1]) + ev1.y, 0.f);
            acc.z += fmaxf(bf2f((ushort_t)xv0[2]) + ev0.z, 0.f) + fmaxf(bf2f((ushort_t)xv1[2]) + ev1.z, 0.f);
            acc.w += fmaxf(bf2f((ushort_t)xv0[3]) + ev0.w, 0.f) + fmaxf(bf2f((ushort_t)xv1[3]) + ev1.w, 0.f);
        }
        if (p < p1) {
            int e0 = epack[p];
            short4v xv0 = *(const short4v*)(h + (size_t)(e0 >> 9) * KP1 + slot * 4);
            float4 ev0 = b4[(size_t)(e0 & 511) * 75 + slot];
            acc.x += fmaxf(bf2f((ushort_t)xv0[0]) + ev0.x, 0.f);
            acc.y += fmaxf(bf2f((ushort_t)xv0[1]) + ev0.y, 0.f);
            acc.z += fmaxf(bf2f((ushort_t)xv0[2]) + ev0.z, 0.f);
            acc.w += fmaxf(bf2f((ushort_t)xv0[3]) + ev0.w, 0.f);
        }
    }
    short4v bv4;
    bv4[0] = (short)bf16_of(acc.x);
    bv4[1] = (short)bf16_of(acc.y);
    bv4[2] = (short)bf16_of(acc.z);
    bv4[3] = (short)bf16_of(acc.w);
    *(short4v*)(aggB + (size_t)n * KP1 + slot * 4) = bv4;   // slots 75..79 zero the pad cols
}

// ---------------- MFMA GEMM: bf16 A,B; 128x128 tile; 2-stage LDS; XCD swizzle ----------------
// KPA = A row stride (defines k-tile count), KPB = B row stride (>= KPA; extra rows must be zero-pad)
#define BMg 128
#define BNg 128

__global__ __launch_bounds__(256) void gemm_as(
    const ushort_t* __restrict__ A, int KPA,
    const ushort_t* __restrict__ B, int KPB,
    const float* __restrict__ bias, const float* __restrict__ gg,
    const float* __restrict__ bb, const float* __restrict__ bm,
    const float* __restrict__ bv,
    int Mc, int NnReal, int relu, int nb, int mb,
    float* __restrict__ outF, int ldF,
    ushort_t* __restrict__ outB, int ldP)
{
    __shared__ ushort_t sA[2][BMg * 32];   // 2 x 8 KB
    __shared__ ushort_t sB[2][BNg * 32];   // 2 x 8 KB  (32 KB total -> 5 blocks/CU)

    // XCD-aware swizzle: same m-strip lands consecutively on one XCD
    int id = blockIdx.x;
    int hi = id / (8 * nb);
    int rem = id - hi * 8 * nb;
    int xcd = rem & 7;
    int nblk = rem >> 3;
    int mblk = hi * 8 + xcd;
    if (mblk >= mb) return;

    const int tid = threadIdx.x;
    const int lane = tid & 63;
    const int w = tid >> 6;
    const int m0 = mblk * BMg;
    const int n0 = nblk * BNg;
    const int wm = (w & 1) * 64;
    const int wn = (w >> 1) * 64;

    const ushort_t* gA[2];
    const ushort_t* gB[2];
    int lbase[2];
#pragma unroll
    for (int i = 0; i < 2; ++i) {
        int s = tid + 256 * i;
        int m = s >> 2, qp = s & 3;
        int q = (qp - (m >> 1)) & 3;
        int msrc = (m0 + m < Mc) ? (m0 + m) : (Mc - 1);
        gA[i] = A + (size_t)msrc * KPA + 8 * q;
        gB[i] = B + (size_t)(n0 + m) * KPB + 8 * q;   // B rows fully padded
        lbase[i] = (w * 64 + 256 * i) * 8;
    }

    f32x4 acc[4][4];
#pragma unroll
    for (int a = 0; a < 4; ++a)
#pragma unroll
        for (int b = 0; b < 4; ++b) acc[a][b] = (f32x4)(0.f);

    const int q = lane >> 4;
    const int c16 = lane & 15;
    const int kt = KPA >> 5;

    // prefetch tile 0 -> stage 0
#pragma unroll
    for (int i = 0; i < 2; ++i) {
        dma16(gA[i], sA[0] + lbase[i]); gA[i] += 32;
        dma16(gB[i], sB[0] + lbase[i]); gB[i] += 32;
    }
    __syncthreads();

    for (int t = 0; t < kt; ++t) {
        int cur = t & 1, nxt = cur ^ 1;
        if (t + 1 < kt) {
#pragma unroll
            for (int i = 0; i < 2; ++i) {
                dma16(gA[i], sA[nxt] + lbase[i]); gA[i] += 32;
                dma16(gB[i], sB[nxt] + lbase[i]); gB[i] += 32;
            }
        }
        short8 av[4], bhv[4];
#pragma unroll
        for (int tt = 0; tt < 4; ++tt) {
            int m = wm + tt * 16 + c16;
            int q2 = (q + (m >> 1)) & 3;
            av[tt] = *(const short8*)(sA[cur] + m * 32 + q2 * 8);
        }
#pragma unroll
        for (int uu = 0; uu < 4; ++uu) {
            int n = wn + uu * 16 + c16;
            int q2 = (q + (n >> 1)) & 3;
            bhv[uu] = *(const short8*)(sB[cur] + n * 32 + q2 * 8);
        }
#pragma unroll
        for (int tt = 0; tt < 4; ++tt)
#pragma unroll
            for (int uu = 0; uu < 4; ++uu)
                acc[tt][uu] = __builtin_amdgcn_mfma_f32_16x16x32_bf16(av[tt], bhv[uu], acc[tt][uu], 0, 0, 0);
        __syncthreads();
    }

    // epilogue: C/D layout col=lane&15, row=q*4+r
#pragma unroll
    for (int uu = 0; uu < 4; ++uu) {
        int gn = n0 + wn + uu * 16 + c16;
        float sc = 0.f, sh = 0.f;
        if (gn < NnReal) {
            sc = gg[gn] * rsqrtf(bv[gn] + 1e-5f);
            sh = bb[gn] + (bias[gn] - bm[gn]) * sc;
        }
#pragma unroll
        for (int tt = 0; tt < 4; ++tt) {
            int rbase = m0 + wm + tt * 16 + q * 4;
#pragma unroll
            for (int r = 0; r < 4; ++r) {
                int gm = rbase + r;
                if (gm >= Mc) continue;
                float y = acc[tt][uu][r] * sc + sh;
                if (relu) y = fmaxf(y, 0.f);
                if (outF) {
                    if (gn < NnReal) outF[(size_t)gm * ldF + gn] = y;
                } else {
                    if (gn < ldP) outB[(size_t)gm * ldP + gn] = bf16_of(y);  // pad cols get 0
                }
            }
        }
    }
}

// ---------------- host-side MLP ----------------

struct MlpP {
    const float *b1, *g1, *be1, *m1, *v1;
    const float *b2, *g2, *be2, *m2, *v2;
};

static void run_mlp(hipStream_t stream, const ushort_t* inB, int M,
                    const ushort_t* wh, int mlp,
                    ushort_t* tB, int CH,
                    const MlpP& W, ushort_t* outB, int relu2) {
    const ushort_t* w1 = wh + (size_t)mlp * WPER;
    const ushort_t* w2 = w1 + NP1 * KP1;
    for (int c0 = 0; c0 < M; c0 += CH) {
        int Mc = (M - c0 < CH) ? (M - c0) : CH;
        int mb = cdiv(Mc, BMg);
        int mbp = cdiv(mb, 8) * 8;
        {
            int nb = NP1 / BNg;   // 5
            gemm_as<<<nb * mbp, 256, 0, stream>>>(
                inB + (size_t)c0 * KP1, KP1, w1, KP1,
                W.b1, W.g1, W.be1, W.m1, W.v1,
                Mc, 2 * EMBD, 1, nb, mb,
                nullptr, 0, tB, KT2);
        }
        {
            int nb = NP2 / BNg;   // 3
            gemm_as<<<nb * mbp, 256, 0, stream>>>(
                tB, KT2, w2, KP2,
                W.b2, W.g2, W.be2, W.m2, W.v2,
                Mc, EMBD, relu2, nb, mb,
                nullptr, 0, outB + (size_t)c0 * KP1, KP1);
        }
    }
}

// ---------------- entry ----------------

extern "C" void kernel_launch(void* const* d_in, const int* in_sizes, int n_in,
                              void* d_out, int out_size, void* d_ws, size_t ws_size,
                              hipStream_t stream) {
    const int*   x        = (const int*)d_in[0];
    const int*   ei       = (const int*)d_in[1];
    const int*   ea       = (const int*)d_in[2];
    const int*   batch    = (const int*)d_in[3];
    const float* atom_emb = (const float*)d_in[4];
    const float* bond_emb = (const float*)d_in[5];
    const float* vn_emb   = (const float*)d_in[6];
    const float* gin_eps  = (const float*)d_in[7];
    const float* gin_W1   = (const float*)d_in[8];
    const float* gin_b1   = (const float*)d_in[9];
    const float* gin_bn1g = (const float*)d_in[10];
    const float* gin_bn1b = (const float*)d_in[11];
    const float* gin_bn1m = (const float*)d_in[12];
    const float* gin_bn1v = (const float*)d_in[13];
    const float* gin_W2   = (const float*)d_in[14];
    const float* gin_b2   = (const float*)d_in[15];
    const float* bn_g     = (const float*)d_in[16];
    const float* bn_b     = (const float*)d_in[17];
    const float* bn_m     = (const float*)d_in[18];
    const float* bn_v     = (const float*)d_in[19];
    const float* vn_W1    = (const float*)d_in[20];
    const float* vn_b1    = (const float*)d_in[21];
    const float* vn_bn1g  = (const float*)d_in[22];
    const float* vn_bn1b  = (const float*)d_in[23];
    const float* vn_bn1m  = (const float*)d_in[24];
    const float* vn_bn1v  = (const float*)d_in[25];
    const float* vn_W2    = (const float*)d_in[26];
    const float* vn_b2    = (const float*)d_in[27];
    const float* vn_bn2g  = (const float*)d_in[28];
    const float* vn_bn2b  = (const float*)d_in[29];
    const float* vn_bn2m  = (const float*)d_in[30];
    const float* vn_bn2v  = (const float*)d_in[31];

    const int N = in_sizes[3];
    const int E = in_sizes[1] / 2;
    const int NB = cdiv(N, 1024);

    // ---- workspace layout (bytes); fixed ~146 MB of the ~256 MiB budget ----
    char* base = (char*)d_ws;
    size_t off = 0;
    ushort_t* hbuf = (ushort_t*)(base + off); off += (size_t)N * KP1 * 2;    // 64 MB
    ushort_t* aggB = (ushort_t*)(base + off); off += (size_t)N * KP1 * 2;    // 64 MB
    float* vnbuf   = (float*)(base + off);    off += (size_t)GG * EMBD * 4;  // 4.9 MB
    int*   starts  = (int*)(base + off);      off += 4104 * 4;
    int*   cnt     = (int*)(base + off);      off += (size_t)N * 4;          // doubles as cursor
    int*   estart  = (int*)(base + off);      off += ((size_t)N + 8) * 4;
    int*   bsum    = (int*)(base + off);      off += 1032 * 4;
    int*   epack   = (int*)(base + off);      off += (size_t)E * 4;          // 1 MB packed
    float* ebsum   = (float*)(base + off);    off += (size_t)512 * EMBD * 4; // 0.6 MB
    ushort_t* whA  = (ushort_t*)(base + off); off += (size_t)9 * WPER * 2;   // 8.1 MB
    ushort_t* vnaB = (ushort_t*)(base + off); off += (size_t)GG * KP1 * 2;   // 2.6 MB
    off = (off + 255) & ~(size_t)255;

    // adaptive chunk for tB: KT2*2 = 1216 B per row; prefer single chunk, else 2 balanced
    size_t avail = (ws_size > off) ? ws_size - off : 0;
    int CH = (int)(avail / (KT2 * 2));
    CH &= ~255;
    if (CH >= N) CH = (N + 255) & ~255;                              // single chunk
    else if (CH >= (N + 1) / 2) CH = (((N + 1) / 2) + 255) & ~255;   // 2 balanced chunks
    if (CH < 2048) CH = 2048;  // last resort
    ushort_t* tB = (ushort_t*)(base + off);

    const int BLK = 256;
    int ne4 = N * 75;

    // ---- one-time init ----
    find_starts<<<cdiv(GG + 1, BLK), BLK, 0, stream>>>(batch, starts, N);
    atom_encode_bf<<<cdiv(ne4, BLK), BLK, 0, stream>>>(x, atom_emb, hbuf, N);
    init_vn4<<<cdiv(GG * 75, BLK), BLK, 0, stream>>>(vn_emb, vnbuf);
    bond_combo<<<cdiv(512 * EMBD, BLK), BLK, 0, stream>>>(bond_emb, ebsum);
    conv_all<<<cdiv(9 * WPER, BLK), BLK, 0, stream>>>(gin_W1, gin_W2, vn_W1, vn_W2, whA);
    hipMemsetAsync(cnt, 0, (size_t)N * 4, stream);
    hipMemsetAsync(vnaB, 0, (size_t)GG * KP1 * 2, stream);
    ecount<<<cdiv(E, BLK), BLK, 0, stream>>>(ei, cnt, E);
    scan_part<<<NB, 256, 0, stream>>>(cnt, bsum, N);
    scan_top<<<1, 1024, 0, stream>>>(bsum, NB);
    scan_final<<<NB, 256, 0, stream>>>(cnt, bsum, estart, cnt /*cursor*/, N, E);
    escatter<<<cdiv(E, BLK), BLK, 0, stream>>>(ei, ea, cnt /*cursor*/, epack, E);

    for (int l = 0; l < NLAY; ++l) {
        int last = (l == NLAY - 1);

        if (!last)
            pool_prep<<<GG / 4, 320, 0, stream>>>(hbuf, vnbuf, starts, vnaB);
        else
            prep_vn<<<cdiv(ne4, BLK), BLK, 0, stream>>>(hbuf, vnbuf, batch, N);

        aggregate<<<cdiv(N, NPB), NPB * 80, 0, stream>>>(
            hbuf, ebsum, estart, epack, gin_eps + l, aggB, N);

        MlpP Wn = { gin_b1 + (size_t)l * 2 * EMBD,
                    gin_bn1g + (size_t)l * 2 * EMBD, gin_bn1b + (size_t)l * 2 * EMBD,
                    gin_bn1m + (size_t)l * 2 * EMBD, gin_bn1v + (size_t)l * 2 * EMBD,
                    gin_b2 + (size_t)l * EMBD,
                    bn_g + (size_t)l * EMBD, bn_b + (size_t)l * EMBD,
                    bn_m + (size_t)l * EMBD, bn_v + (size_t)l * EMBD };
        run_mlp(stream, aggB, N, whA, l, tB, CH, Wn, hbuf, last ? 0 : 1);

        if (!last) {
            const ushort_t* w1 = whA + (size_t)(NLAY + l) * WPER;
            const ushort_t* w2 = w1 + NP1 * KP1;
            int mb = cdiv(GG, BMg), mbp = cdiv(mb, 8) * 8;
            gemm_as<<<(NP1 / BNg) * mbp, 256, 0, stream>>>(
                vnaB, KP1, w1, KP1,
                vn_b1 + (size_t)l * 2 * EMBD, vn_bn1g + (size_t)l * 2 * EMBD,
                vn_bn1b + (size_t)l * 2 * EMBD, vn_bn1m + (size_t)l * 2 * EMBD,
                vn_bn1v + (size_t)l * 2 * EMBD,
                GG, 2 * EMBD, 1, NP1 / BNg, mb,
                nullptr, 0, tB, KT2);
            gemm_as<<<(NP2 / BNg) * mbp, 256, 0, stream>>>(
                tB, KT2, w2, KP2,
                vn_b2 + (size_t)l * EMBD, vn_bn2g + (size_t)l * EMBD,
                vn_bn2b + (size_t)l * EMBD, vn_bn2m + (size_t)l * EMBD,
                vn_bn2v + (size_t)l * EMBD,
                GG, EMBD, 1, NP2 / BNg, mb,
                vnbuf, EMBD, nullptr, 0);
        }
    }

    pool_mean<<<GG / 4, 320, 0, stream>>>(hbuf, starts, (float*)d_out);
}

// Round 15
// 1559.402 us; speedup vs baseline: 1.4480x; 1.1215x over previous
//
#include <hip/hip_runtime.h>
#include <hip/hip_bf16.h>

#define EMBD 300
#define GG   4096
#define NLAY 5
#define KP1  320   // padded K for EMB=300 inputs (h / aggB row stride)
#define KP2  640   // W2 weight-plane K stride
#define KT2  608   // t-buffer row stride (19 x 32)
#define NP1  640   // padded out-cols for 600
#define NP2  384   // padded out-cols for 300 (3 x 128)
#define WPER (NP1*KP1 + NP2*KP2)   // 450560 elems per MLP weight set

typedef unsigned short ushort_t;
typedef short short8 __attribute__((ext_vector_type(8)));
typedef short short4v __attribute__((ext_vector_type(4)));
typedef float f32x4 __attribute__((ext_vector_type(4)));

static inline int cdiv(int a, int b) { return (a + b - 1) / b; }

// ---------------- helpers ----------------

__device__ inline void dma16(const ushort_t* g, ushort_t* l) {
    __builtin_amdgcn_global_load_lds(
        (const __attribute__((address_space(1))) unsigned int*)g,
        (__attribute__((address_space(3))) unsigned int*)l, 16, 0, 0);
}

__device__ inline ushort_t bf16_of(float v) {
    union { __hip_bfloat16 b; ushort_t u; } c;
    c.b = __float2bfloat16(v);
    return c.u;
}

__device__ inline float bf2f(ushort_t u) {
    union { unsigned int i; float f; } c;
    c.i = ((unsigned int)u) << 16;
    return c.f;
}

// ---------------- init kernels ----------------

__global__ void atom_encode_bf(const int* __restrict__ x, const float* __restrict__ aemb,
                               ushort_t* __restrict__ h, int N) {
    int i = blockIdx.x * blockDim.x + threadIdx.x;
    int total = N * 75;
    if (i >= total) return;
    int n = i / 75, d4 = i - n * 75;
    const int* xr = x + n * 9;
    float4 s = make_float4(0.f, 0.f, 0.f, 0.f);
    const float4* a4 = (const float4*)aemb;
#pragma unroll
    for (int f = 0; f < 9; ++f) {
        float4 v = a4[(size_t)((f << 7) + xr[f]) * 75 + d4];
        s.x += v.x; s.y += v.y; s.z += v.z; s.w += v.w;
    }
    short4v o;
    o[0] = (short)bf16_of(s.x); o[1] = (short)bf16_of(s.y);
    o[2] = (short)bf16_of(s.z); o[3] = (short)bf16_of(s.w);
    *(short4v*)(h + (size_t)n * KP1 + d4 * 4) = o;
}

__global__ void init_vn4(const float* __restrict__ vn_emb, float* __restrict__ vn) {
    int i = blockIdx.x * blockDim.x + threadIdx.x;
    if (i >= GG * 75) return;
    ((float4*)vn)[i] = ((const float4*)vn_emb)[i % 75];
}

__global__ void find_starts(const int* __restrict__ batch, int* __restrict__ starts, int N) {
    int g = blockIdx.x * blockDim.x + threadIdx.x;
    if (g > GG) return;
    int lo = 0, hi = N;
    while (lo < hi) {
        int mid = (lo + hi) >> 1;
        if (batch[mid] < g) lo = mid + 1; else hi = mid;
    }
    starts[g] = lo;
}

__global__ void bond_combo(const float* __restrict__ bemb, float* __restrict__ ebsum) {
    int i = blockIdx.x * blockDim.x + threadIdx.x;
    if (i >= 512 * EMBD) return;
    int c = i / EMBD, d = i - c * EMBD;
    int a0 = c >> 6, a1 = (c >> 3) & 7, a2 = c & 7;
    ebsum[i] = bemb[a0 * EMBD + d] + bemb[(8 + a1) * EMBD + d] + bemb[(16 + a2) * EMBD + d];
}

__global__ void conv_all(const float* __restrict__ gW1, const float* __restrict__ gW2,
                         const float* __restrict__ vW1, const float* __restrict__ vW2,
                         ushort_t* __restrict__ wh) {
    int i = blockIdx.x * blockDim.x + threadIdx.x;
    int total = WPER * 9;
    if (i >= total) return;
    int mlp = i / WPER, r = i - mlp * WPER;
    const float *W1, *W2;
    if (mlp < NLAY) {
        W1 = gW1 + (size_t)mlp * EMBD * 2 * EMBD;
        W2 = gW2 + (size_t)mlp * 2 * EMBD * EMBD;
    } else {
        int l = mlp - NLAY;
        W1 = vW1 + (size_t)l * EMBD * 2 * EMBD;
        W2 = vW2 + (size_t)l * 2 * EMBD * EMBD;
    }
    float v;
    if (r < NP1 * KP1) {
        int n = r / KP1, k = r - n * KP1;
        v = (n < 2 * EMBD && k < EMBD) ? W1[(size_t)k * (2 * EMBD) + n] : 0.f;
    } else {
        int r2 = r - NP1 * KP1;
        int n = r2 / KP2, k = r2 - n * KP2;
        v = (n < EMBD && k < 2 * EMBD) ? W2[(size_t)k * EMBD + n] : 0.f;
    }
    wh[i] = bf16_of(v);
}

// ---------------- edge bucket sort ----------------

__global__ void ecount(const int* __restrict__ ei, int* __restrict__ cnt, int E) {
    int e = blockIdx.x * blockDim.x + threadIdx.x;
    if (e >= E) return;
    atomicAdd(&cnt[ei[E + e]], 1);
}

__global__ void scan_part(const int* __restrict__ cnt, int* __restrict__ bsum, int N) {
    __shared__ int sh[256];
    int b = blockIdx.x, t = threadIdx.x;
    int base = b * 1024;
    int s = 0;
    for (int j = t; j < 1024; j += 256) {
        int idx = base + j;
        if (idx < N) s += cnt[idx];
    }
    sh[t] = s;
    __syncthreads();
    for (int d = 128; d > 0; d >>= 1) {
        if (t < d) sh[t] += sh[t + d];
        __syncthreads();
    }
    if (t == 0) bsum[b] = sh[0];
}

__global__ void scan_top(int* __restrict__ bsum, int nb) {
    __shared__ int sh[1024];
    int t = threadIdx.x;
    int v = (t < nb) ? bsum[t] : 0;
    sh[t] = v;
    __syncthreads();
    for (int d = 1; d < 1024; d <<= 1) {
        int u = (t >= d) ? sh[t - d] : 0;
        __syncthreads();
        sh[t] += u;
        __syncthreads();
    }
    if (t < nb) bsum[t] = sh[t] - v;  // exclusive
}

__global__ void scan_final(int* __restrict__ cnt, const int* __restrict__ bsum,
                           int* __restrict__ estart, int* __restrict__ cursor, int N, int E) {
    __shared__ int sh[256];
    int b = blockIdx.x, t = threadIdx.x;
    int base = b * 1024 + t * 4;
    int c[4];
    int s = 0;
#pragma unroll
    for (int j = 0; j < 4; ++j) {
        int idx = base + j;
        c[j] = (idx < N) ? cnt[idx] : 0;
        s += c[j];
    }
    sh[t] = s;
    __syncthreads();
    for (int d = 1; d < 256; d <<= 1) {
        int u = (t >= d) ? sh[t - d] : 0;
        __syncthreads();
        sh[t] += u;
        __syncthreads();
    }
    int run = sh[t] - s + bsum[b];
#pragma unroll
    for (int j = 0; j < 4; ++j) {
        int idx = base + j;
        if (idx < N) { estart[idx] = run; cursor[idx] = run; run += c[j]; }
    }
    if (b == 0 && t == 0) estart[N] = E;
}

__global__ void escatter(const int* __restrict__ ei, const int* __restrict__ ea,
                         int* __restrict__ cursor, int* __restrict__ epack, int E) {
    int e = blockIdx.x * blockDim.x + threadIdx.x;
    if (e >= E) return;
    int c = ei[E + e];
    int p = atomicAdd(&cursor[c], 1);
    epack[p] = (ei[e] << 9) | (ea[3 * e] << 6) | (ea[3 * e + 1] << 3) | ea[3 * e + 2];
}

// ---------------- fused per-layer elementwise (h is bf16 [N][KP1]) ----------------

__global__ void pool_prep(ushort_t* __restrict__ h, const float* __restrict__ vn,
                          const int* __restrict__ starts, ushort_t* __restrict__ vnaB) {
    int g = blockIdx.x * 4 + threadIdx.x / 80;
    int slot = threadIdx.x % 80;
    if (g >= GG || slot >= 75) return;
    float4 vng = ((const float4*)vn)[(size_t)g * 75 + slot];
    int s0 = starts[g], s1 = starts[g + 1];
    float4 s = make_float4(0.f, 0.f, 0.f, 0.f);
    for (int n = s0; n < s1; ++n) {
        short4v* hp = (short4v*)(h + (size_t)n * KP1 + slot * 4);
        short4v hv = *hp;
        float v0 = bf2f((ushort_t)hv[0]) + vng.x;
        float v1 = bf2f((ushort_t)hv[1]) + vng.y;
        float v2 = bf2f((ushort_t)hv[2]) + vng.z;
        float v3 = bf2f((ushort_t)hv[3]) + vng.w;
        short4v o;
        o[0] = (short)bf16_of(v0); o[1] = (short)bf16_of(v1);
        o[2] = (short)bf16_of(v2); o[3] = (short)bf16_of(v3);
        *hp = o;
        s.x += v0; s.y += v1; s.z += v2; s.w += v3;
    }
    short4v o;
    o[0] = (short)bf16_of(s.x + vng.x); o[1] = (short)bf16_of(s.y + vng.y);
    o[2] = (short)bf16_of(s.z + vng.z); o[3] = (short)bf16_of(s.w + vng.w);
    *(short4v*)(vnaB + (size_t)g * KP1 + slot * 4) = o;
}

__global__ void prep_vn(ushort_t* __restrict__ h, const float* __restrict__ vn,
                        const int* __restrict__ batch, int N) {
    int i = blockIdx.x * blockDim.x + threadIdx.x;
    int total = N * 75;
    if (i >= total) return;
    int n = i / 75, d4 = i - n * 75;
    float4 vv = ((const float4*)vn)[(size_t)batch[n] * 75 + d4];
    short4v hv = *(short4v*)(h + (size_t)n * KP1 + d4 * 4);
    short4v o;
    o[0] = (short)bf16_of(bf2f((ushort_t)hv[0]) + vv.x);
    o[1] = (short)bf16_of(bf2f((ushort_t)hv[1]) + vv.y);
    o[2] = (short)bf16_of(bf2f((ushort_t)hv[2]) + vv.z);
    o[3] = (short)bf16_of(bf2f((ushort_t)hv[3]) + vv.w);
    *(short4v*)(h + (size_t)n * KP1 + d4 * 4) = o;
}

__global__ void pool_mean(const ushort_t* __restrict__ h, const int* __restrict__ starts,
                          float* __restrict__ out) {
    int g = blockIdx.x * 4 + threadIdx.x / 80;
    int slot = threadIdx.x % 80;
    if (g >= GG || slot >= 75) return;
    int s0 = starts[g], s1 = starts[g + 1];
    float4 s = make_float4(0.f, 0.f, 0.f, 0.f);
    for (int n = s0; n < s1; ++n) {
        short4v hv = *(const short4v*)(h + (size_t)n * KP1 + slot * 4);
        s.x += bf2f((ushort_t)hv[0]);
        s.y += bf2f((ushort_t)hv[1]);
        s.z += bf2f((ushort_t)hv[2]);
        s.w += bf2f((ushort_t)hv[3]);
    }
    float inv = 1.0f / fmaxf((float)(s1 - s0), 1.0f);
    float4 o = make_float4(s.x * inv, s.y * inv, s.z * inv, s.w * inv);
    ((float4*)out)[(size_t)g * 75 + slot] = o;
}

// ---------------- fused aggregate (2-edge unroll, packed epack) ----------------
#define NPB 4   // nodes per block; blockDim = NPB*80 = 320

__global__ void aggregate(const ushort_t* __restrict__ h, const float* __restrict__ ebsum,
                          const int* __restrict__ estart, const int* __restrict__ epack,
                          const float* __restrict__ epsp,
                          ushort_t* __restrict__ aggB, int N) {
    int n = blockIdx.x * NPB + threadIdx.x / 80;
    int slot = threadIdx.x % 80;
    if (n >= N) return;
    float4 acc = make_float4(0.f, 0.f, 0.f, 0.f);
    if (slot < 75) {
        const float4* b4 = (const float4*)ebsum;
        float ce = 1.0f + *epsp;
        short4v hv = *(const short4v*)(h + (size_t)n * KP1 + slot * 4);
        acc.x = ce * bf2f((ushort_t)hv[0]);
        acc.y = ce * bf2f((ushort_t)hv[1]);
        acc.z = ce * bf2f((ushort_t)hv[2]);
        acc.w = ce * bf2f((ushort_t)hv[3]);
        int p0 = estart[n], p1 = estart[n + 1];
        int p = p0;
        for (; p + 2 <= p1; p += 2) {
            int e0 = epack[p], e1 = epack[p + 1];
            short4v xv0 = *(const short4v*)(h + (size_t)(e0 >> 9) * KP1 + slot * 4);
            short4v xv1 = *(const short4v*)(h + (size_t)(e1 >> 9) * KP1 + slot * 4);
            float4 ev0 = b4[(size_t)(e0 & 511) * 75 + slot];
            float4 ev1 = b4[(size_t)(e1 & 511) * 75 + slot];
            acc.x += fmaxf(bf2f((ushort_t)xv0[0]) + ev0.x, 0.f) + fmaxf(bf2f((ushort_t)xv1[0]) + ev1.x, 0.f);
            acc.y += fmaxf(bf2f((ushort_t)xv0[1]) + ev0.y, 0.f) + fmaxf(bf2f((ushort_t)xv1[1]) + ev1.y, 0.f);
            acc.z += fmaxf(bf2f((ushort_t)xv0[2]) + ev0.z, 0.f) + fmaxf(bf2f((ushort_t)xv1[2]) + ev1.z, 0.f);
            acc.w += fmaxf(bf2f((ushort_t)xv0[3]) + ev0.w, 0.f) + fmaxf(bf2f((ushort_t)xv1[3]) + ev1.w, 0.f);
        }
        if (p < p1) {
            int e0 = epack[p];
            short4v xv0 = *(const short4v*)(h + (size_t)(e0 >> 9) * KP1 + slot * 4);
            float4 ev0 = b4[(size_t)(e0 & 511) * 75 + slot];
            acc.x += fmaxf(bf2f((ushort_t)xv0[0]) + ev0.x, 0.f);
            acc.y += fmaxf(bf2f((ushort_t)xv0[1]) + ev0.y, 0.f);
            acc.z += fmaxf(bf2f((ushort_t)xv0[2]) + ev0.z, 0.f);
            acc.w += fmaxf(bf2f((ushort_t)xv0[3]) + ev0.w, 0.f);
        }
    }
    short4v bv4;
    bv4[0] = (short)bf16_of(acc.x);
    bv4[1] = (short)bf16_of(acc.y);
    bv4[2] = (short)bf16_of(acc.z);
    bv4[3] = (short)bf16_of(acc.w);
    *(short4v*)(aggB + (size_t)n * KP1 + slot * 4) = bv4;
}

// ---------------- MFMA GEMM: bf16 A,B; 128x128 tile; 2-stage LDS; XCD swizzle ----------------
// bf16 output path uses LDS-staged full-line stores (kills HBM write amplification).
// NOTE: no local pointer-arrays into LDS (addrspacecast static-init is unsupported);
// stages addressed via integer offsets off the single smem symbol.
#define BMg 128
#define BNg 128
#define STG (BMg * 32)   // elems per stage plane

__global__ __launch_bounds__(256) void gemm_as(
    const ushort_t* __restrict__ A, int KPA,
    const ushort_t* __restrict__ B, int KPB,
    const float* __restrict__ bias, const float* __restrict__ gg,
    const float* __restrict__ bb, const float* __restrict__ bm,
    const float* __restrict__ bv,
    int Mc, int NnReal, int relu, int nb, int mb,
    float* __restrict__ outF, int ldF,
    ushort_t* __restrict__ outB, int ldP)
{
    __shared__ ushort_t smem[4 * STG];   // 32 KB: [A0|A1|B0|B1] during K-loop; C-tile after

    // XCD-aware swizzle: same m-strip lands consecutively on one XCD
    int id = blockIdx.x;
    int hi = id / (8 * nb);
    int rem = id - hi * 8 * nb;
    int xcd = rem & 7;
    int nblk = rem >> 3;
    int mblk = hi * 8 + xcd;
    if (mblk >= mb) return;

    const int tid = threadIdx.x;
    const int lane = tid & 63;
    const int w = tid >> 6;
    const int m0 = mblk * BMg;
    const int n0 = nblk * BNg;
    const int wm = (w & 1) * 64;
    const int wn = (w >> 1) * 64;

    const ushort_t* gA[2];
    const ushort_t* gB[2];
    int lbase[2];
#pragma unroll
    for (int i = 0; i < 2; ++i) {
        int s = tid + 256 * i;
        int m = s >> 2, qp = s & 3;
        int q = (qp - (m >> 1)) & 3;
        int msrc = (m0 + m < Mc) ? (m0 + m) : (Mc - 1);
        gA[i] = A + (size_t)msrc * KPA + 8 * q;
        gB[i] = B + (size_t)(n0 + m) * KPB + 8 * q;   // B rows fully padded
        lbase[i] = (w * 64 + 256 * i) * 8;
    }

    f32x4 acc[4][4];
#pragma unroll
    for (int a = 0; a < 4; ++a)
#pragma unroll
        for (int b = 0; b < 4; ++b) acc[a][b] = (f32x4)(0.f);

    const int q = lane >> 4;
    const int c16 = lane & 15;
    const int kt = KPA >> 5;

    // prefetch tile 0 -> stage 0
#pragma unroll
    for (int i = 0; i < 2; ++i) {
        dma16(gA[i], smem + lbase[i]);           gA[i] += 32;
        dma16(gB[i], smem + 2 * STG + lbase[i]); gB[i] += 32;
    }
    __syncthreads();

    for (int t = 0; t < kt; ++t) {
        int cur = t & 1, nxt = cur ^ 1;
        if (t + 1 < kt) {
#pragma unroll
            for (int i = 0; i < 2; ++i) {
                dma16(gA[i], smem + nxt * STG + lbase[i]);       gA[i] += 32;
                dma16(gB[i], smem + (2 + nxt) * STG + lbase[i]); gB[i] += 32;
            }
        }
        const ushort_t* sAc = smem + cur * STG;
        const ushort_t* sBc = smem + (2 + cur) * STG;
        short8 av[4], bhv[4];
#pragma unroll
        for (int tt = 0; tt < 4; ++tt) {
            int m = wm + tt * 16 + c16;
            int q2 = (q + (m >> 1)) & 3;
            av[tt] = *(const short8*)(sAc + m * 32 + q2 * 8);
        }
#pragma unroll
        for (int uu = 0; uu < 4; ++uu) {
            int n = wn + uu * 16 + c16;
            int q2 = (q + (n >> 1)) & 3;
            bhv[uu] = *(const short8*)(sBc + n * 32 + q2 * 8);
        }
#pragma unroll
        for (int tt = 0; tt < 4; ++tt)
#pragma unroll
            for (int uu = 0; uu < 4; ++uu)
                acc[tt][uu] = __builtin_amdgcn_mfma_f32_16x16x32_bf16(av[tt], bhv[uu], acc[tt][uu], 0, 0, 0);
        __syncthreads();
    }

    // ---- epilogue: bn (+relu); C/D layout col=lane&15, row=q*4+r ----
    float sc[4], sh[4];
#pragma unroll
    for (int uu = 0; uu < 4; ++uu) {
        int gn = n0 + wn + uu * 16 + c16;
        if (gn < NnReal) {
            float s = gg[gn] * rsqrtf(bv[gn] + 1e-5f);
            sc[uu] = s;
            sh[uu] = bb[gn] + (bias[gn] - bm[gn]) * sc[uu];
        } else { sc[uu] = 0.f; sh[uu] = 0.f; }
    }

    if (outB) {
        // stage C tile in LDS (bf16, q*16-column rotation for bank spread), then
        // full-line stores: each wave instruction = 4 x 256B aligned contiguous segments.
        const int rot = q * 16;
#pragma unroll
        for (int uu = 0; uu < 4; ++uu) {
#pragma unroll
            for (int tt = 0; tt < 4; ++tt) {
                int row = wm + tt * 16 + q * 4;
#pragma unroll
                for (int r = 0; r < 4; ++r) {
                    float y = acc[tt][uu][r] * sc[uu] + sh[uu];
                    if (relu) y = fmaxf(y, 0.f);
                    int col_s = (wn + uu * 16 + c16 + rot) & 127;
                    smem[(row + r) * 128 + col_s] = bf16_of(y);
                }
            }
        }
        __syncthreads();
#pragma unroll
        for (int j = 0; j < 8; ++j) {
            int row = j * 16 + q * 4 + w;          // (row>>2)&3 == q -> matches writer rotation
            int gm = m0 + row;
            int gcl = c16 * 8;
            if (gm < Mc && n0 + gcl + 8 <= ldP) {
                short8 v = *(const short8*)(smem + row * 128 + ((gcl + rot) & 127));
                *(short8*)(outB + (size_t)gm * ldP + n0 + gcl) = v;
            }
        }
    } else {
#pragma unroll
        for (int uu = 0; uu < 4; ++uu) {
            int gn = n0 + wn + uu * 16 + c16;
#pragma unroll
            for (int tt = 0; tt < 4; ++tt) {
                int rbase = m0 + wm + tt * 16 + q * 4;
#pragma unroll
                for (int r = 0; r < 4; ++r) {
                    int gm = rbase + r;
                    if (gm >= Mc) continue;
                    float y = acc[tt][uu][r] * sc[uu] + sh[uu];
                    if (relu) y = fmaxf(y, 0.f);
                    if (gn < NnReal) outF[(size_t)gm * ldF + gn] = y;
                }
            }
        }
    }
}

// ---------------- host-side MLP ----------------

struct MlpP {
    const float *b1, *g1, *be1, *m1, *v1;
    const float *b2, *g2, *be2, *m2, *v2;
};

static void run_mlp(hipStream_t stream, const ushort_t* inB, int M,
                    const ushort_t* wh, int mlp,
                    ushort_t* tB, int CH,
                    const MlpP& W, ushort_t* outB, int relu2) {
    const ushort_t* w1 = wh + (size_t)mlp * WPER;
    const ushort_t* w2 = w1 + NP1 * KP1;
    for (int c0 = 0; c0 < M; c0 += CH) {
        int Mc = (M - c0 < CH) ? (M - c0) : CH;
        int mb = cdiv(Mc, BMg);
        int mbp = cdiv(mb, 8) * 8;
        {
            int nb = NP1 / BNg;   // 5
            gemm_as<<<nb * mbp, 256, 0, stream>>>(
                inB + (size_t)c0 * KP1, KP1, w1, KP1,
                W.b1, W.g1, W.be1, W.m1, W.v1,
                Mc, 2 * EMBD, 1, nb, mb,
                nullptr, 0, tB, KT2);
        }
        {
            int nb = NP2 / BNg;   // 3
            gemm_as<<<nb * mbp, 256, 0, stream>>>(
                tB, KT2, w2, KP2,
                W.b2, W.g2, W.be2, W.m2, W.v2,
                Mc, EMBD, relu2, nb, mb,
                nullptr, 0, outB + (size_t)c0 * KP1, KP1);
        }
    }
}

// ---------------- entry ----------------

extern "C" void kernel_launch(void* const* d_in, const int* in_sizes, int n_in,
                              void* d_out, int out_size, void* d_ws, size_t ws_size,
                              hipStream_t stream) {
    const int*   x        = (const int*)d_in[0];
    const int*   ei       = (const int*)d_in[1];
    const int*   ea       = (const int*)d_in[2];
    const int*   batch    = (const int*)d_in[3];
    const float* atom_emb = (const float*)d_in[4];
    const float* bond_emb = (const float*)d_in[5];
    const float* vn_emb   = (const float*)d_in[6];
    const float* gin_eps  = (const float*)d_in[7];
    const float* gin_W1   = (const float*)d_in[8];
    const float* gin_b1   = (const float*)d_in[9];
    const float* gin_bn1g = (const float*)d_in[10];
    const float* gin_bn1b = (const float*)d_in[11];
    const float* gin_bn1m = (const float*)d_in[12];
    const float* gin_bn1v = (const float*)d_in[13];
    const float* gin_W2   = (const float*)d_in[14];
    const float* gin_b2   = (const float*)d_in[15];
    const float* bn_g     = (const float*)d_in[16];
    const float* bn_b     = (const float*)d_in[17];
    const float* bn_m     = (const float*)d_in[18];
    const float* bn_v     = (const float*)d_in[19];
    const float* vn_W1    = (const float*)d_in[20];
    const float* vn_b1    = (const float*)d_in[21];
    const float* vn_bn1g  = (const float*)d_in[22];
    const float* vn_bn1b  = (const float*)d_in[23];
    const float* vn_bn1m  = (const float*)d_in[24];
    const float* vn_bn1v  = (const float*)d_in[25];
    const float* vn_W2    = (const float*)d_in[26];
    const float* vn_b2    = (const float*)d_in[27];
    const float* vn_bn2g  = (const float*)d_in[28];
    const float* vn_bn2b  = (const float*)d_in[29];
    const float* vn_bn2m  = (const float*)d_in[30];
    const float* vn_bn2v  = (const float*)d_in[31];

    const int N = in_sizes[3];
    const int E = in_sizes[1] / 2;
    const int NB = cdiv(N, 1024);

    // ---- workspace layout (bytes); fixed ~146 MB of the ~256 MiB budget ----
    char* base = (char*)d_ws;
    size_t off = 0;
    ushort_t* hbuf = (ushort_t*)(base + off); off += (size_t)N * KP1 * 2;    // 64 MB
    ushort_t* aggB = (ushort_t*)(base + off); off += (size_t)N * KP1 * 2;    // 64 MB
    float* vnbuf   = (float*)(base + off);    off += (size_t)GG * EMBD * 4;  // 4.9 MB
    int*   starts  = (int*)(base + off);      off += 4104 * 4;
    int*   cnt     = (int*)(base + off);      off += (size_t)N * 4;          // doubles as cursor
    int*   estart  = (int*)(base + off);      off += ((size_t)N + 8) * 4;
    int*   bsum    = (int*)(base + off);      off += 1032 * 4;
    int*   epack   = (int*)(base + off);      off += (size_t)E * 4;          // 1 MB packed
    float* ebsum   = (float*)(base + off);    off += (size_t)512 * EMBD * 4; // 0.6 MB
    ushort_t* whA  = (ushort_t*)(base + off); off += (size_t)9 * WPER * 2;   // 8.1 MB
    ushort_t* vnaB = (ushort_t*)(base + off); off += (size_t)GG * KP1 * 2;   // 2.6 MB
    off = (off + 255) & ~(size_t)255;

    // adaptive chunk for tB: KT2*2 = 1216 B per row; prefer single chunk, else 2 balanced
    size_t avail = (ws_size > off) ? ws_size - off : 0;
    int CH = (int)(avail / (KT2 * 2));
    CH &= ~255;
    if (CH >= N) CH = (N + 255) & ~255;                              // single chunk
    else if (CH >= (N + 1) / 2) CH = (((N + 1) / 2) + 255) & ~255;   // 2 balanced chunks
    if (CH < 2048) CH = 2048;  // last resort
    ushort_t* tB = (ushort_t*)(base + off);

    const int BLK = 256;
    int ne4 = N * 75;

    // ---- one-time init ----
    find_starts<<<cdiv(GG + 1, BLK), BLK, 0, stream>>>(batch, starts, N);
    atom_encode_bf<<<cdiv(ne4, BLK), BLK, 0, stream>>>(x, atom_emb, hbuf, N);
    init_vn4<<<cdiv(GG * 75, BLK), BLK, 0, stream>>>(vn_emb, vnbuf);
    bond_combo<<<cdiv(512 * EMBD, BLK), BLK, 0, stream>>>(bond_emb, ebsum);
    conv_all<<<cdiv(9 * WPER, BLK), BLK, 0, stream>>>(gin_W1, gin_W2, vn_W1, vn_W2, whA);
    (void)hipMemsetAsync(cnt, 0, (size_t)N * 4, stream);
    (void)hipMemsetAsync(vnaB, 0, (size_t)GG * KP1 * 2, stream);
    ecount<<<cdiv(E, BLK), BLK, 0, stream>>>(ei, cnt, E);
    scan_part<<<NB, 256, 0, stream>>>(cnt, bsum, N);
    scan_top<<<1, 1024, 0, stream>>>(bsum, NB);
    scan_final<<<NB, 256, 0, stream>>>(cnt, bsum, estart, cnt /*cursor*/, N, E);
    escatter<<<cdiv(E, BLK), BLK, 0, stream>>>(ei, ea, cnt /*cursor*/, epack, E);

    for (int l = 0; l < NLAY; ++l) {
        int last = (l == NLAY - 1);

        if (!last)
            pool_prep<<<GG / 4, 320, 0, stream>>>(hbuf, vnbuf, starts, vnaB);
        else
            prep_vn<<<cdiv(ne4, BLK), BLK, 0, stream>>>(hbuf, vnbuf, batch, N);

        aggregate<<<cdiv(N, NPB), NPB * 80, 0, stream>>>(
            hbuf, ebsum, estart, epack, gin_eps + l, aggB, N);

        MlpP Wn = { gin_b1 + (size_t)l * 2 * EMBD,
                    gin_bn1g + (size_t)l * 2 * EMBD, gin_bn1b + (size_t)l * 2 * EMBD,
                    gin_bn1m + (size_t)l * 2 * EMBD, gin_bn1v + (size_t)l * 2 * EMBD,
                    gin_b2 + (size_t)l * EMBD,
                    bn_g + (size_t)l * EMBD, bn_b + (size_t)l * EMBD,
                    bn_m + (size_t)l * EMBD, bn_v + (size_t)l * EMBD };
        run_mlp(stream, aggB, N, whA, l, tB, CH, Wn, hbuf, last ? 0 : 1);

        if (!last) {
            const ushort_t* w1 = whA + (size_t)(NLAY + l) * WPER;
            const ushort_t* w2 = w1 + NP1 * KP1;
            int mb = cdiv(GG, BMg), mbp = cdiv(mb, 8) * 8;
            gemm_as<<<(NP1 / BNg) * mbp, 256, 0, stream>>>(
                vnaB, KP1, w1, KP1,
                vn_b1 + (size_t)l * 2 * EMBD, vn_bn1g + (size_t)l * 2 * EMBD,
                vn_bn1b + (size_t)l * 2 * EMBD, vn_bn1m + (size_t)l * 2 * EMBD,
                vn_bn1v + (size_t)l * 2 * EMBD,
                GG, 2 * EMBD, 1, NP1 / BNg, mb,
                nullptr, 0, tB, KT2);
            gemm_as<<<(NP2 / BNg) * mbp, 256, 0, stream>>>(
                tB, KT2, w2, KP2,
                vn_b2 + (size_t)l * EMBD, vn_bn2g + (size_t)l * EMBD,
                vn_bn2b + (size_t)l * EMBD, vn_bn2m + (size_t)l * EMBD,
                vn_bn2v + (size_t)l * EMBD,
                GG, EMBD, 1, NP2 / BNg, mb,
                vnbuf, EMBD, nullptr, 0);
        }
    }

    pool_mean<<<GG / 4, 320, 0, stream>>>(hbuf, starts, (float*)d_out);
}